// Round 1
// baseline (18147.072 us; speedup 1.0000x reference)
//
#include <hip/hip_runtime.h>
#include <stdint.h>
#include <math.h>

#define N_PART 8192
#define T_STEPS 1024
#define KNOTS 130          // evaluated knots k=0..129 in u-space (u=k/128)
#define TABW 131           // +1 ghost at idx0 (k=-1, mirror of k=+1)
#define MTOT (T_STEPS*KNOTS)

// ---------------- Threefry-2x32 (exact JAX semantics) ----------------
__device__ __forceinline__ uint32_t rotl32(uint32_t x, int d){ return (x<<d)|(x>>(32-d)); }

__device__ __forceinline__ void tf2x32(uint32_t k0, uint32_t k1, uint32_t c0, uint32_t c1,
                                       uint32_t& o0, uint32_t& o1){
  uint32_t ks2 = k0 ^ k1 ^ 0x1BD11BDAu;
  uint32_t x0 = c0 + k0, x1 = c1 + k1;
  #define TFR(r) { x0 += x1; x1 = rotl32(x1, r); x1 ^= x0; }
  TFR(13) TFR(15) TFR(26) TFR(6)
  x0 += k1;  x1 += ks2 + 1u;
  TFR(17) TFR(29) TFR(16) TFR(24)
  x0 += ks2; x1 += k0 + 2u;
  TFR(13) TFR(15) TFR(26) TFR(6)
  x0 += k0;  x1 += k1 + 3u;
  TFR(17) TFR(29) TFR(16) TFR(24)
  x0 += k1;  x1 += ks2 + 4u;
  TFR(13) TFR(15) TFR(26) TFR(6)
  x0 += ks2; x1 += k0 + 5u;
  #undef TFR
  o0 = x0; o1 = x1;
}

// XLA f32 erf_inv (Giles polynomial)
__device__ __forceinline__ float erfinv_xla(float x){
  float w = -log1pf(-x*x);
  float p;
  if (w < 5.0f){
    w -= 2.5f;
    p = 2.81022636e-08f;
    p = fmaf(p, w, 3.43273939e-07f);
    p = fmaf(p, w, -3.5233877e-06f);
    p = fmaf(p, w, -4.39150654e-06f);
    p = fmaf(p, w, 0.00021858087f);
    p = fmaf(p, w, -0.00125372503f);
    p = fmaf(p, w, -0.00417768164f);
    p = fmaf(p, w, 0.246640727f);
    p = fmaf(p, w, 1.50140941f);
  } else {
    w = sqrtf(w) - 3.0f;
    p = -0.000200214257f;
    p = fmaf(p, w, 0.000100950558f);
    p = fmaf(p, w, 0.00134934322f);
    p = fmaf(p, w, -0.00367342844f);
    p = fmaf(p, w, 0.00573950773f);
    p = fmaf(p, w, -0.0076224613f);
    p = fmaf(p, w, 0.00943887047f);
    p = fmaf(p, w, 1.00167406f);
    p = fmaf(p, w, 2.83297682f);
  }
  return p * x;
}

// ---------------- kernel 1: derive per-step keys + u0 ----------------
// base=key(42)=(0,42); kA=fold_in(base,0)=tf(base,(0,0)); kB=fold_in(base,1)=tf(base,(0,1))
// split(key,T): flat = [r0(i) i<T] ++ [r1(i) i<T], cipher i uses ctr=(i,T+i); key_t=(flat[2t],flat[2t+1])
__global__ void k_keys(uint32_t* __restrict__ knKeys, float* __restrict__ u0Tab){
  int t = blockIdx.x*blockDim.x + threadIdx.x;
  if (t >= T_STEPS) return;
  uint32_t kA0,kA1,kB0,kB1;
  tf2x32(0u,42u, 0u,0u, kA0,kA1);
  tf2x32(0u,42u, 0u,1u, kB0,kB1);

  auto splitElem = [&](uint32_t kk0, uint32_t kk1, int idx)->uint32_t{
    uint32_t o0,o1;
    if (idx < T_STEPS){ tf2x32(kk0,kk1,(uint32_t)idx,(uint32_t)(T_STEPS+idx),o0,o1); return o0; }
    int i = idx - T_STEPS;
    tf2x32(kk0,kk1,(uint32_t)i,(uint32_t)(T_STEPS+i),o0,o1); return o1;
  };
  uint32_t n0 = splitElem(kA0,kA1, 2*t);
  uint32_t n1 = splitElem(kA0,kA1, 2*t+1);
  uint32_t r0 = splitElem(kB0,kB1, 2*t);
  uint32_t r1 = splitElem(kB0,kB1, 2*t+1);
  knKeys[2*t] = n0; knKeys[2*t+1] = n1;
  // uniform scalar: size 1 (odd) -> padded ctr (0,0), take o0
  uint32_t o0,o1; tf2x32(r0,r1,0u,0u,o0,o1);
  u0Tab[t] = __uint_as_float((o0>>9) | 0x3f800000u) - 1.0f;
}

// ---------------- kernel 2: noise table (F_STD * normal) ----------------
// random_bits for size 8192: bits[i]=r0 of cipher(i,4096+i) for i<4096; bits[4096+i]=r1
__global__ void k_noise(const uint32_t* __restrict__ knKeys, float* __restrict__ noiseTab){
  int t = blockIdx.x;
  uint32_t k0 = knKeys[2*t], k1 = knKeys[2*t+1];
  const int half = N_PART/2;
  const float lo = -0.99999994f;           // nextafter(-1,0)
  for (int i = threadIdx.x; i < half; i += blockDim.x){
    uint32_t o0,o1; tf2x32(k0,k1,(uint32_t)i,(uint32_t)(half+i),o0,o1);
    float ua = __uint_as_float((o0>>9)|0x3f800000u) - 1.0f;
    float ub = __uint_as_float((o1>>9)|0x3f800000u) - 1.0f;
    float va = fmaxf(lo, ua*2.0f + lo);    // (hi-lo) rounds to exactly 2.0f
    float vb = fmaxf(lo, ub*2.0f + lo);
    float na = 1.4142135623730951f * erfinv_xla(va);
    float nb = 1.4142135623730951f * erfinv_xla(vb);
    noiseTab[(size_t)t*N_PART + i]        = 0.005f * na;
    noiseTab[(size_t)t*N_PART + half + i] = 0.005f * nb;
  }
}

// ---------------- kernel 3: knot MLP GEMM (layer1 fused, layer2 tiled, layer3 epilogue) ----------------
// rows m = t*130+k; A[m][j] = sigmoid(soc_m*W1[j,0] + sI_t*W1[j,1] + b1[j]) generated on the fly
// C = A @ W2^T ; epilogue: Zpart[ntile][m] = sum_n W3[n]*sigmoid(C+b2)
__global__ __launch_bounds__(256) void k_knot_gemm(
    const float* __restrict__ current, const float* __restrict__ W1,
    const float* __restrict__ b1, const float* __restrict__ W2,
    const float* __restrict__ b2, const float* __restrict__ W3,
    float* __restrict__ Zpart)
{
  __shared__ float sA[32][64];
  __shared__ float sB[32][129];
  __shared__ float sSoc[64], sSI[64];
  __shared__ float sRed[64][17];

  const int tid = threadIdx.x;
  const int m0 = blockIdx.x * 64;
  const int n0 = blockIdx.y * 128;

  if (tid < 64){
    int mrow = m0 + tid;
    int t = mrow / 130;
    int k = mrow - t*130;
    float u = (float)k * (1.0f/128.0f);
    sSoc[tid] = u*u;                       // exact in f32
    sSI[tid]  = (current[t] + 2.0f) * 0.25f;
  }
  __syncthreads();

  const int tx = tid & 15;   // n: 8 each
  const int ty = tid >> 4;   // m: 4 each
  float acc[4][8];
  #pragma unroll
  for (int i=0;i<4;i++)
    #pragma unroll
    for (int q=0;q<8;q++) acc[i][q] = 0.0f;

  for (int kc = 0; kc < 1024; kc += 32){
    { // generate A tile
      int base = tid*8;
      int jj = base >> 6;
      int mm = base & 63;
      int j = kc + jj;
      float w0 = W1[2*j], w1v = W1[2*j+1], bb = b1[j];
      #pragma unroll
      for (int e=0;e<8;e++){
        int m = mm + e;
        float pre = sSoc[m]*w0 + sSI[m]*w1v + bb;
        sA[jj][m] = 1.0f/(1.0f + expf(-pre));
      }
    }
    { // load B tile: W2[n0..n0+127][kc..kc+31]
      int nl = tid & 127;
      int h  = tid >> 7;
      const float* src = W2 + (size_t)(n0 + nl)*1024 + kc + h*16;
      float4 v0 = *(const float4*)(src+0);
      float4 v1 = *(const float4*)(src+4);
      float4 v2 = *(const float4*)(src+8);
      float4 v3 = *(const float4*)(src+12);
      int kb = h*16;
      sB[kb+ 0][nl]=v0.x; sB[kb+ 1][nl]=v0.y; sB[kb+ 2][nl]=v0.z; sB[kb+ 3][nl]=v0.w;
      sB[kb+ 4][nl]=v1.x; sB[kb+ 5][nl]=v1.y; sB[kb+ 6][nl]=v1.z; sB[kb+ 7][nl]=v1.w;
      sB[kb+ 8][nl]=v2.x; sB[kb+ 9][nl]=v2.y; sB[kb+10][nl]=v2.z; sB[kb+11][nl]=v2.w;
      sB[kb+12][nl]=v3.x; sB[kb+13][nl]=v3.y; sB[kb+14][nl]=v3.z; sB[kb+15][nl]=v3.w;
    }
    __syncthreads();
    #pragma unroll
    for (int kk=0;kk<32;kk++){
      float a_[4], b_[8];
      #pragma unroll
      for (int i=0;i<4;i++) a_[i] = sA[kk][ty*4+i];
      #pragma unroll
      for (int q=0;q<8;q++) b_[q] = sB[kk][tx*8+q];
      #pragma unroll
      for (int i=0;i<4;i++)
        #pragma unroll
        for (int q=0;q<8;q++) acc[i][q] = fmaf(a_[i], b_[q], acc[i][q]);
    }
    __syncthreads();
  }
  // epilogue
  float part[4] = {0.f,0.f,0.f,0.f};
  #pragma unroll
  for (int q=0;q<8;q++){
    int n = n0 + tx*8 + q;
    float bb = b2[n], w3 = W3[n];
    #pragma unroll
    for (int i=0;i<4;i++){
      float h = 1.0f/(1.0f + expf(-(acc[i][q] + bb)));
      part[i] = fmaf(w3, h, part[i]);
    }
  }
  #pragma unroll
  for (int i=0;i<4;i++) sRed[ty*4+i][tx] = part[i];
  __syncthreads();
  if (tid < 64){
    float s = 0.0f;
    #pragma unroll
    for (int x=0;x<16;x++) s += sRed[tid][x];
    Zpart[(size_t)blockIdx.y*MTOT + m0 + tid] = s;
  }
}

// ---------------- kernel 4: combine Zparts + voc -> V table ----------------
__global__ void k_tab(const float* __restrict__ Zpart, const float* __restrict__ current,
                      const float* __restrict__ b3, float* __restrict__ Tab){
  int mrow = blockIdx.x*blockDim.x + threadIdx.x;
  if (mrow >= MTOT) return;
  int t = mrow / 130;
  int k = mrow - t*130;
  float z = ((Zpart[mrow] + Zpart[MTOT+mrow]) + Zpart[2*MTOT+mrow]) + Zpart[3*MTOT+mrow] + b3[0];
  double u = (double)k / 128.0;
  double s = u*u;
  const double vL=-1.59614486, v0=4.13646328, gam=0.63726463, alp=1.40174122, bet=2.54478965;
  double voc = vL + (v0-vL)*exp(gam*(s-1.0)) + alp*vL*(s-1.0)
             + (1.0-alp)*vL*(exp(-bet) - exp(-bet*sqrt(s)));
  float G = (float)voc - current[t]*z;
  Tab[t*TABW + k + 1] = G;
  if (k == 1) Tab[t*TABW + 0] = G;   // mirror ghost (even in u)
}

// cubic Lagrange through knots c-1..c+2 on the u grid (table idx = knot+1)
__device__ __forceinline__ float interpV(const float* __restrict__ tab, float s){
  float u = sqrtf(s);
  float x = u * 128.0f;
  int c = (int)x;
  if (c > 127) c = 127;
  float xi = x - (float)c;
  float y0 = tab[c], y1 = tab[c+1], y2 = tab[c+2], y3 = tab[c+3];
  float xm1 = xi - 1.0f, xm2 = xi - 2.0f, xp1 = xi + 1.0f;
  float w0 = -(1.0f/6.0f) * xi  * xm1 * xm2;
  float w1 =  0.5f        * xp1 * xm1 * xm2;
  float w2 = -0.5f        * xi  * xp1 * xm2;
  float w3 =  (1.0f/6.0f) * xi  * xp1 * xm1;
  return ((w0*y0 + w1*y1) + w2*y2) + w3*y3;
}

// ---------------- kernel 5: the sequential particle filter (single block) ----------------
__global__ __launch_bounds__(1024) void k_filter(
    const float* __restrict__ soc_init, const float* __restrict__ current,
    const float* __restrict__ vmeas,   const float* __restrict__ Ecrit,
    const float* __restrict__ Tab,     const float* __restrict__ noiseTab,
    const float* __restrict__ u0Tab,
    float* __restrict__ vHist, float* __restrict__ sHist,
    long strideT, long strideP, float* __restrict__ lossOut)
{
  __shared__ __align__(16) float socProp[N_PART];   // 32 KiB
  __shared__ __align__(16) float Cum[N_PART];       // 32 KiB (also scratch: dS f64 region, tabRow at +512)
  double* dS = (double*)Cum;
  float* tabS = Cum + 512;

  const int tid = threadIdx.x;
  const int lane = tid & 63;
  const int wv = tid >> 6;
  const float ec = Ecrit[0];

  float soc[8], V[8];

  // init: V0 = voc(soc_init) - I0*Z0 via table row 0
  if (tid < TABW) tabS[tid] = Tab[tid];
  __syncthreads();
  #pragma unroll
  for (int k=0;k<8;k++){
    float s = soc_init[tid*8+k];
    soc[k] = s;
    V[k] = interpV(tabS, s);
  }
  float loss = 0.0f;
  float Iprev = current[0];

  for (int t=0; t<T_STEPS; t++){
    __syncthreads();                       // protect Cum/tabS region from prev iteration
    if (tid < TABW) tabS[tid] = Tab[t*TABW + tid];
    __syncthreads();                       // B0

    float It = current[t];
    float vm = vmeas[t];
    float u0 = u0Tab[t];
    const float4* nz4 = (const float4*)(noiseTab + (size_t)t*N_PART + tid*8);
    float4 nza = nz4[0], nzb = nz4[1];
    float nz[8] = {nza.x,nza.y,nza.z,nza.w,nzb.x,nzb.y,nzb.z,nzb.w};

    float lw[8];
    float lmax = -INFINITY;
    #pragma unroll
    for (int k=0;k<8;k++){
      float s = soc[k];
      float tmp = Iprev * V[k];
      tmp = tmp / 26267.160775850585f;     // E_CRIT_NEW (f32)
      tmp = tmp * ec;
      s = s - tmp;
      s = s + nz[k];
      s = (s > 1.0f) ? 1.0f : ((s < 0.0f) ? 1e-10f : s);
      socProp[tid*8+k] = s;
      float Vn = interpV(tabS, s);
      V[k] = Vn;
      float d = (Vn - vm) / 0.01f;
      lw[k] = 3.6863734722137451f - 0.5f*(d*d);   // log(NU)
      lmax = fmaxf(lmax, lw[k]);
    }
    if (strideP == 1){
      float4 a = {V[0],V[1],V[2],V[3]}, b = {V[4],V[5],V[6],V[7]};
      float4* dst = (float4*)(vHist + (size_t)t*strideT + tid*8);
      dst[0] = a; dst[1] = b;
    } else {
      #pragma unroll
      for (int k=0;k<8;k++) vHist[(size_t)t*strideT + (size_t)(tid*8+k)*strideP] = V[k];
    }
    // global max (exact)
    #pragma unroll
    for (int off=1; off<64; off<<=1) lmax = fmaxf(lmax, __shfl_xor(lmax, off));
    if (lane == 0) Cum[wv] = lmax;
    __syncthreads();                       // B1
    float gmax = Cum[0];
    #pragma unroll
    for (int i=1;i<16;i++) gmax = fmaxf(gmax, Cum[i]);

    // exp + f64 prefix sums
    double cpref[8];
    double run = 0.0;
    #pragma unroll
    for (int k=0;k<8;k++){
      float e = expf(lw[k] - gmax);
      run += (double)e;
      cpref[k] = run;
    }
    double sc = run;
    #pragma unroll
    for (int off=1; off<64; off<<=1){
      double o = __shfl_up(sc, (unsigned)off);
      if (lane >= off) sc += o;
    }
    double myWaveExcl = sc - run;
    if (lane == 63) dS[64+wv] = sc;        // wave totals (floats 128..159, clear of Cum[0..15] & tabS)
    __syncthreads();                       // B2
    if (tid < 16){
      double v = dS[64+tid];
      double s2 = v;
      #pragma unroll
      for (int off=1; off<16; off<<=1){
        double o = __shfl_up(s2, (unsigned)off);
        if (lane >= off) s2 += o;
      }
      dS[80+tid] = s2 - v;                 // exclusive wave offsets
      if (tid == 15) dS[96] = s2;          // total
    }
    __syncthreads();                       // B3
    double waveOff = dS[80+wv];
    double S = dS[96];
    double invS = 1.0 / S;
    double base = waveOff + myWaveExcl;
    float Cf[8];
    #pragma unroll
    for (int k=0;k<8;k++) Cf[k] = (float)((base + cpref[k]) * invS);
    if (tid == 0)
      loss = ((loss + gmax) + (float)log(S)) - 9.0109134742136256f;  // log(8192)
    __syncthreads();                       // B4 (all dS reads done before float writes)
    #pragma unroll
    for (int k=0;k<8;k++) Cum[tid*8+k] = Cf[k];
    __syncthreads();                       // B5

    // systematic resample: per-slot binary search (searchsorted left + clip)
    {
      const float sc8 = 1.0f/8192.0f;
      float sn[8];
      #pragma unroll
      for (int k=0;k<8;k++){
        float pos = (u0 + (float)(tid*8+k)) * sc8;
        int lo = 0, hi = N_PART;
        while (hi > lo){
          int mid = (lo + hi) >> 1;
          if (Cum[mid] < pos) lo = mid + 1; else hi = mid;
        }
        int a = lo < N_PART ? lo : (N_PART-1);
        sn[k] = socProp[a];
      }
      #pragma unroll
      for (int k=0;k<8;k++) soc[k] = sn[k];
      if (strideP == 1){
        float4 a = {sn[0],sn[1],sn[2],sn[3]}, b = {sn[4],sn[5],sn[6],sn[7]};
        float4* dst = (float4*)(sHist + (size_t)t*strideT + tid*8);
        dst[0] = a; dst[1] = b;
      } else {
        #pragma unroll
        for (int k=0;k<8;k++) sHist[(size_t)t*strideT + (size_t)(tid*8+k)*strideP] = sn[k];
      }
    }
    Iprev = It;
    __syncthreads();                       // B6 (WAR on socProp/Cum)
  }
  if (tid == 0) lossOut[0] = loss;
}

// ---------------- kernel 6: (T,N) -> (N,T) transpose for both histories ----------------
__global__ void k_transpose(const float* __restrict__ vS, const float* __restrict__ sS,
                            float* __restrict__ outV, float* __restrict__ outS){
  __shared__ float tile[32][33];
  const float* src = blockIdx.z ? sS : vS;
  float* dst = blockIdx.z ? outS : outV;
  int t0 = blockIdx.x*32, n0 = blockIdx.y*32;
  int tx = threadIdx.x, ty = threadIdx.y;
  #pragma unroll
  for (int r=0;r<4;r++)
    tile[ty+8*r][tx] = src[(size_t)(t0+ty+8*r)*N_PART + n0 + tx];
  __syncthreads();
  #pragma unroll
  for (int r=0;r<4;r++)
    dst[(size_t)(n0+ty+8*r)*T_STEPS + t0 + tx] = tile[tx][ty+8*r];
}

extern "C" void kernel_launch(void* const* d_in, const int* in_sizes, int n_in,
                              void* d_out, int out_size, void* d_ws, size_t ws_size,
                              hipStream_t stream){
  const float* soc_init = (const float*)d_in[0];
  const float* current  = (const float*)d_in[1];
  const float* vmeas    = (const float*)d_in[2];
  const float* W1 = (const float*)d_in[3];
  const float* b1 = (const float*)d_in[4];
  const float* W2 = (const float*)d_in[5];
  const float* b2 = (const float*)d_in[6];
  const float* W3 = (const float*)d_in[7];
  const float* b3 = (const float*)d_in[8];
  const float* Ec = (const float*)d_in[9];

  float* outLoss = (float*)d_out;
  float* outV = outLoss + 1;
  float* outS = outV + (size_t)N_PART*T_STEPS;

  char* p = (char*)d_ws;
  auto carve = [&](size_t bytes)->char*{ char* r = p; p += (bytes + 255) & ~(size_t)255; return r; };
  uint32_t* knKeys  = (uint32_t*)carve((size_t)2*T_STEPS*4);
  float* u0Tab      = (float*)carve((size_t)T_STEPS*4);
  float* Tab        = (float*)carve((size_t)T_STEPS*TABW*4);
  float* Zpart      = (float*)carve((size_t)4*MTOT*4);
  float* noiseTab   = (float*)carve((size_t)N_PART*T_STEPS*4);
  float* vS         = (float*)carve((size_t)N_PART*T_STEPS*4);
  float* sS         = (float*)carve((size_t)N_PART*T_STEPS*4);
  bool useScratch   = ((size_t)(p - (char*)d_ws) <= ws_size);

  k_keys<<<dim3((T_STEPS+255)/256), dim3(256), 0, stream>>>(knKeys, u0Tab);
  k_noise<<<dim3(T_STEPS), dim3(256), 0, stream>>>(knKeys, noiseTab);
  k_knot_gemm<<<dim3(MTOT/64, 4), dim3(256), 0, stream>>>(current, W1, b1, W2, b2, W3, Zpart);
  k_tab<<<dim3((MTOT+255)/256), dim3(256), 0, stream>>>(Zpart, current, b3, Tab);

  if (useScratch){
    k_filter<<<dim3(1), dim3(1024), 0, stream>>>(soc_init, current, vmeas, Ec, Tab, noiseTab,
                                                 u0Tab, vS, sS, (long)N_PART, 1L, outLoss);
    k_transpose<<<dim3(T_STEPS/32, N_PART/32, 2), dim3(32,8), 0, stream>>>(vS, sS, outV, outS);
  } else {
    k_filter<<<dim3(1), dim3(1024), 0, stream>>>(soc_init, current, vmeas, Ec, Tab, noiseTab,
                                                 u0Tab, outV, outS, 1L, (long)T_STEPS, outLoss);
  }
}

// Round 2
// 12461.795 us; speedup vs baseline: 1.4562x; 1.4562x over previous
//
#include <hip/hip_runtime.h>
#include <stdint.h>
#include <math.h>

#define N_PART 8192
#define T_STEPS 1024
#define UKNOTS 130            // u-knots k=0..129, u=k/128
#define SIKNOTS 68            // sI-knots j=0..67, sI = SI_LO + j*SI_H
#define M2TOT (UKNOTS*SIKNOTS)   // 8840 GEMM rows
#define SI_LO 0.49375f
#define SI_H  0.00625f

// ---------------- Threefry-2x32 (exact JAX semantics) ----------------
__device__ __forceinline__ uint32_t rotl32(uint32_t x, int d){ return (x<<d)|(x>>(32-d)); }

__device__ __forceinline__ void tf2x32(uint32_t k0, uint32_t k1, uint32_t c0, uint32_t c1,
                                       uint32_t& o0, uint32_t& o1){
  uint32_t ks2 = k0 ^ k1 ^ 0x1BD11BDAu;
  uint32_t x0 = c0 + k0, x1 = c1 + k1;
  #define TFR(r) { x0 += x1; x1 = rotl32(x1, r); x1 ^= x0; }
  TFR(13) TFR(15) TFR(26) TFR(6)
  x0 += k1;  x1 += ks2 + 1u;
  TFR(17) TFR(29) TFR(16) TFR(24)
  x0 += ks2; x1 += k0 + 2u;
  TFR(13) TFR(15) TFR(26) TFR(6)
  x0 += k0;  x1 += k1 + 3u;
  TFR(17) TFR(29) TFR(16) TFR(24)
  x0 += k1;  x1 += ks2 + 4u;
  TFR(13) TFR(15) TFR(26) TFR(6)
  x0 += ks2; x1 += k0 + 5u;
  #undef TFR
  o0 = x0; o1 = x1;
}

__device__ __forceinline__ float erfinv_xla(float x){
  float w = -log1pf(-x*x);
  float p;
  if (w < 5.0f){
    w -= 2.5f;
    p = 2.81022636e-08f;
    p = fmaf(p, w, 3.43273939e-07f);
    p = fmaf(p, w, -3.5233877e-06f);
    p = fmaf(p, w, -4.39150654e-06f);
    p = fmaf(p, w, 0.00021858087f);
    p = fmaf(p, w, -0.00125372503f);
    p = fmaf(p, w, -0.00417768164f);
    p = fmaf(p, w, 0.246640727f);
    p = fmaf(p, w, 1.50140941f);
  } else {
    w = sqrtf(w) - 3.0f;
    p = -0.000200214257f;
    p = fmaf(p, w, 0.000100950558f);
    p = fmaf(p, w, 0.00134934322f);
    p = fmaf(p, w, -0.00367342844f);
    p = fmaf(p, w, 0.00573950773f);
    p = fmaf(p, w, -0.0076224613f);
    p = fmaf(p, w, 0.00943887047f);
    p = fmaf(p, w, 1.00167406f);
    p = fmaf(p, w, 2.83297682f);
  }
  return p * x;
}

// ---------------- kernel 1: per-step keys + u0 ----------------
__global__ void k_keys(uint32_t* __restrict__ knKeys, float* __restrict__ u0Tab){
  int t = blockIdx.x*blockDim.x + threadIdx.x;
  if (t >= T_STEPS) return;
  uint32_t kA0,kA1,kB0,kB1;
  tf2x32(0u,42u, 0u,0u, kA0,kA1);
  tf2x32(0u,42u, 0u,1u, kB0,kB1);
  auto splitElem = [&](uint32_t kk0, uint32_t kk1, int idx)->uint32_t{
    uint32_t o0,o1;
    if (idx < T_STEPS){ tf2x32(kk0,kk1,(uint32_t)idx,(uint32_t)(T_STEPS+idx),o0,o1); return o0; }
    int i = idx - T_STEPS;
    tf2x32(kk0,kk1,(uint32_t)i,(uint32_t)(T_STEPS+i),o0,o1); return o1;
  };
  uint32_t n0 = splitElem(kA0,kA1, 2*t);
  uint32_t n1 = splitElem(kA0,kA1, 2*t+1);
  uint32_t r0 = splitElem(kB0,kB1, 2*t);
  uint32_t r1 = splitElem(kB0,kB1, 2*t+1);
  knKeys[2*t] = n0; knKeys[2*t+1] = n1;
  uint32_t o0,o1; tf2x32(r0,r1,0u,0u,o0,o1);
  u0Tab[t] = __uint_as_float((o0>>9) | 0x3f800000u) - 1.0f;
}

// ---------------- kernel 2: noise table ----------------
__global__ void k_noise(const uint32_t* __restrict__ knKeys, float* __restrict__ noiseTab){
  int t = blockIdx.x;
  uint32_t k0 = knKeys[2*t], k1 = knKeys[2*t+1];
  const int half = N_PART/2;
  const float lo = -0.99999994f;
  for (int i = threadIdx.x; i < half; i += blockDim.x){
    uint32_t o0,o1; tf2x32(k0,k1,(uint32_t)i,(uint32_t)(half+i),o0,o1);
    float ua = __uint_as_float((o0>>9)|0x3f800000u) - 1.0f;
    float ub = __uint_as_float((o1>>9)|0x3f800000u) - 1.0f;
    float va = fmaxf(lo, ua*2.0f + lo);
    float vb = fmaxf(lo, ub*2.0f + lo);
    float na = 1.4142135623730951f * erfinv_xla(va);
    float nb = 1.4142135623730951f * erfinv_xla(vb);
    noiseTab[(size_t)t*N_PART + i]        = 0.005f * na;
    noiseTab[(size_t)t*N_PART + half + i] = 0.005f * nb;
  }
}

// ---------------- kernel 3: (u, sI)-grid MLP GEMM ----------------
// rows r = k*68 + j; soc=(k/128)^2, sI=SI_LO+j*SI_H. A on the fly, C = A@W2^T, epilogue W3-reduce.
__global__ __launch_bounds__(256) void k_gemm(
    const float* __restrict__ W1, const float* __restrict__ b1,
    const float* __restrict__ W2, const float* __restrict__ b2,
    const float* __restrict__ W3, float* __restrict__ Zpart)
{
  __shared__ float sA[32][64];
  __shared__ float sB[32][129];
  __shared__ float sSoc[64], sSI[64];
  __shared__ float sRed[64][17];

  const int tid = threadIdx.x;
  const int m0 = blockIdx.x * 64;
  const int n0 = blockIdx.y * 128;

  if (tid < 64){
    int r = m0 + tid; if (r >= M2TOT) r = M2TOT-1;
    int k = r / SIKNOTS;
    int j = r - k*SIKNOTS;
    float u = (float)k * (1.0f/128.0f);
    sSoc[tid] = u*u;
    sSI[tid]  = SI_LO + SI_H * (float)j;
  }
  __syncthreads();

  const int tx = tid & 15;
  const int ty = tid >> 4;
  float acc[4][8];
  #pragma unroll
  for (int i=0;i<4;i++)
    #pragma unroll
    for (int q=0;q<8;q++) acc[i][q] = 0.0f;

  for (int kc = 0; kc < 1024; kc += 32){
    {
      int base = tid*8;
      int jj = base >> 6;
      int mm = base & 63;
      int j = kc + jj;
      float w0 = W1[2*j], w1v = W1[2*j+1], bb = b1[j];
      #pragma unroll
      for (int e=0;e<8;e++){
        int m = mm + e;
        float pre = sSoc[m]*w0 + sSI[m]*w1v + bb;
        sA[jj][m] = 1.0f/(1.0f + expf(-pre));
      }
    }
    {
      int nl = tid & 127;
      int h  = tid >> 7;
      const float* src = W2 + (size_t)(n0 + nl)*1024 + kc + h*16;
      float4 v0 = *(const float4*)(src+0);
      float4 v1 = *(const float4*)(src+4);
      float4 v2 = *(const float4*)(src+8);
      float4 v3 = *(const float4*)(src+12);
      int kb = h*16;
      sB[kb+ 0][nl]=v0.x; sB[kb+ 1][nl]=v0.y; sB[kb+ 2][nl]=v0.z; sB[kb+ 3][nl]=v0.w;
      sB[kb+ 4][nl]=v1.x; sB[kb+ 5][nl]=v1.y; sB[kb+ 6][nl]=v1.z; sB[kb+ 7][nl]=v1.w;
      sB[kb+ 8][nl]=v2.x; sB[kb+ 9][nl]=v2.y; sB[kb+10][nl]=v2.z; sB[kb+11][nl]=v2.w;
      sB[kb+12][nl]=v3.x; sB[kb+13][nl]=v3.y; sB[kb+14][nl]=v3.z; sB[kb+15][nl]=v3.w;
    }
    __syncthreads();
    #pragma unroll
    for (int kk=0;kk<32;kk++){
      float a_[4], b_[8];
      #pragma unroll
      for (int i=0;i<4;i++) a_[i] = sA[kk][ty*4+i];
      #pragma unroll
      for (int q=0;q<8;q++) b_[q] = sB[kk][tx*8+q];
      #pragma unroll
      for (int i=0;i<4;i++)
        #pragma unroll
        for (int q=0;q<8;q++) acc[i][q] = fmaf(a_[i], b_[q], acc[i][q]);
    }
    __syncthreads();
  }
  float part[4] = {0.f,0.f,0.f,0.f};
  #pragma unroll
  for (int q=0;q<8;q++){
    int n = n0 + tx*8 + q;
    float bb = b2[n], w3 = W3[n];
    #pragma unroll
    for (int i=0;i<4;i++){
      float h = 1.0f/(1.0f + expf(-(acc[i][q] + bb)));
      part[i] = fmaf(w3, h, part[i]);
    }
  }
  #pragma unroll
  for (int i=0;i<4;i++) sRed[ty*4+i][tx] = part[i];
  __syncthreads();
  if (tid < 64){
    int r = m0 + tid;
    if (r < M2TOT){
      float s = 0.0f;
      #pragma unroll
      for (int x=0;x<16;x++) s += sRed[tid][x];
      Zpart[(size_t)blockIdx.y*M2TOT + r] = s;
    }
  }
}

// ---------------- kernel 4a: combine Z parts ----------------
__global__ void k_tabZ(const float* __restrict__ Zpart, const float* __restrict__ b3,
                       float* __restrict__ Z2D){
  int r = blockIdx.x*blockDim.x + threadIdx.x;
  if (r >= M2TOT) return;
  Z2D[r] = ((Zpart[r] + Zpart[M2TOT+r]) + Zpart[2*M2TOT+r]) + Zpart[3*M2TOT+r] + b3[0];
}

// ---------------- kernel 4b: per-(t,k) sI-interp + voc -> G table ----------------
__global__ void k_tabG(const float* __restrict__ Z2D, const float* __restrict__ current,
                       float* __restrict__ Gtab){
  int m = blockIdx.x*blockDim.x + threadIdx.x;
  if (m >= T_STEPS*UKNOTS) return;
  int t = m / UKNOTS;
  int k = m - t*UKNOTS;
  float It = current[t];
  float sI = (It + 2.0f) * 0.25f;
  float x = (sI - SI_LO) * (1.0f/SI_H);
  int c = (int)x; if (c < 1) c = 1; if (c > 65) c = 65;
  float xi = x - (float)c;
  const float* zp = Z2D + k*SIKNOTS + (c-1);
  float y0 = zp[0], y1 = zp[1], y2 = zp[2], y3 = zp[3];
  float xm1 = xi - 1.0f, xm2 = xi - 2.0f, xp1 = xi + 1.0f;
  float w0 = -(1.0f/6.0f) * xi  * xm1 * xm2;
  float w1 =  0.5f        * xp1 * xm1 * xm2;
  float w2 = -0.5f        * xi  * xp1 * xm2;
  float w3 =  (1.0f/6.0f) * xi  * xp1 * xm1;
  float z = ((w0*y0 + w1*y1) + w2*y2) + w3*y3;
  double u = (double)k / 128.0;
  double s = u*u;
  const double vL=-1.59614486, v0=4.13646328, gam=0.63726463, alp=1.40174122, bet=2.54478965;
  double voc = vL + (v0-vL)*exp(gam*(s-1.0)) + alp*vL*(s-1.0)
             + (1.0-alp)*vL*(exp(-bet) - exp(-bet*sqrt(s)));
  Gtab[m] = (float)voc - It*z;
}

// ---------------- kernel 4c: 4-wide redundant table Tab4[t][c] = (G[c-1],G[c],G[c+1],G[c+2]) ----------------
__global__ void k_tab4(const float* __restrict__ Gtab, float4* __restrict__ Tab4){
  int m = blockIdx.x*blockDim.x + threadIdx.x;
  if (m >= T_STEPS*128) return;
  int t = m >> 7;
  int c = m & 127;
  const float* g = Gtab + t*UKNOTS;
  float y0 = (c == 0) ? g[1] : g[c-1];   // even mirror in u
  Tab4[m] = make_float4(y0, g[c], g[c+1], g[c+2]);
}

// cubic Lagrange via the 4-wide table: one b128 LDS read
__device__ __forceinline__ float interp4(const float4* __restrict__ tab, float s){
  float x = sqrtf(s) * 128.0f;
  int c = (int)x; if (c > 127) c = 127;
  float xi = x - (float)c;
  float4 Y = tab[c];
  float xm1 = xi - 1.0f, xm2 = xi - 2.0f, xp1 = xi + 1.0f;
  float w0 = -(1.0f/6.0f) * xi  * xm1 * xm2;
  float w1 =  0.5f        * xp1 * xm1 * xm2;
  float w2 = -0.5f        * xi  * xp1 * xm2;
  float w3 =  (1.0f/6.0f) * xi  * xp1 * xm1;
  return ((w0*Y.x + w1*Y.y) + w2*Y.z) + w3*Y.w;
}

// ---------------- kernel 5: sequential particle filter (single block, 1024 thr) ----------------
// Resampling via direct slot inversion: particle i owns slots (a_{i-1}, a_i], a_i = floor(N*Cum_i - u0).
// Scatter start+wave-anchors with LDS atomicMax, wave max-scan, gather. 3 barriers/step.
__global__ __launch_bounds__(1024) void k_filter(
    const float* __restrict__ soc_init, const float* __restrict__ current,
    const float* __restrict__ vmeas,   const float* __restrict__ Ecrit,
    const float4* __restrict__ Tab4,   const float* __restrict__ noiseTab,
    const float* __restrict__ u0Tab,
    float* __restrict__ vHist, float* __restrict__ sHist,
    long strideT, long strideP, float* __restrict__ lossOut)
{
  __shared__ __align__(16) unsigned short socP[N_PART];  // 16 KiB (u16-quantized soc)
  __shared__ __align__(16) int idxA[N_PART];             // 32 KiB
  __shared__ __align__(16) float4 tabS4[128];            // 2 KiB
  __shared__ float  mW[16];
  __shared__ double sW[16];

  const int tid = threadIdx.x;
  const int lane = tid & 63;
  const int wv = tid >> 6;
  const float ec = Ecrit[0];

  // prologue: table row 0 + noise row 0
  if (tid < 128) tabS4[tid] = Tab4[tid];
  const float4* nzp = (const float4*)noiseTab + tid*2;
  float4 nzA = nzp[0], nzB = nzp[1];
  float soc[8], V[8];
  __syncthreads();
  #pragma unroll
  for (int k=0;k<8;k++){
    float s = soc_init[tid*8+k];
    soc[k] = s;
    V[k] = interp4(tabS4, s);
  }
  float loss = 0.0f;
  float Iprev = current[0];

  for (int t=0; t<T_STEPS; t++){
    // ---- phase 1 ----
    int tn = (t+1 < T_STEPS) ? t+1 : t;
    float4 tabPre;
    if (tid < 128) tabPre = Tab4[(size_t)tn*128 + tid];
    const float4* nzn = (const float4*)(noiseTab + (size_t)tn*N_PART) + tid*2;
    float4 nzA2 = nzn[0], nzB2 = nzn[1];

    float It = current[t];
    float vm = vmeas[t];
    float u0 = u0Tab[t];
    float nz[8] = {nzA.x,nzA.y,nzA.z,nzA.w,nzB.x,nzB.y,nzB.z,nzB.w};

    float lw[8];
    float m = -INFINITY;
    #pragma unroll
    for (int k=0;k<8;k++){
      float s = soc[k];
      float tmp = Iprev * V[k];
      tmp = tmp / 26267.160775850585f;
      tmp = tmp * ec;
      s = s - tmp;
      s = s + nz[k];
      s = (s > 1.0f) ? 1.0f : ((s < 0.0f) ? 1e-10f : s);
      socP[tid*8+k] = (unsigned short)__float2int_rn(s * 65535.0f);
      float Vn = interp4(tabS4, s);
      V[k] = Vn;
      float d = (Vn - vm) * 100.0f;
      lw[k] = 3.6862316527834183f - 0.5f*(d*d);   // log(NU)
      m = fmaxf(m, lw[k]);
    }
    if (strideP == 1){
      float4 a = {V[0],V[1],V[2],V[3]}, b = {V[4],V[5],V[6],V[7]};
      float4* dst = (float4*)(vHist + (size_t)t*strideT + tid*8);
      dst[0] = a; dst[1] = b;
    } else {
      #pragma unroll
      for (int k=0;k<8;k++) vHist[(size_t)t*strideT + (size_t)(tid*8+k)*strideP] = V[k];
    }
    { int4 mm1 = {-1,-1,-1,-1}; ((int4*)idxA)[tid*2] = mm1; ((int4*)idxA)[tid*2+1] = mm1; }

    #pragma unroll
    for (int off=1; off<64; off<<=1) m = fmaxf(m, __shfl_xor(m, off));

    double run = 0.0, cp[8];
    #pragma unroll
    for (int k=0;k<8;k++){
      float e = expf(lw[k] - m);
      run += (double)e;
      cp[k] = run;
    }
    double sc = run;
    #pragma unroll
    for (int off=1; off<64; off<<=1){
      double o = __shfl_up(sc, (unsigned)off);
      if (lane >= off) sc += o;
    }
    double excl = sc - run;
    if (lane == 63){ mW[wv] = m; sW[wv] = sc; }
    __syncthreads();                        // B1

    if (tid < 128) tabS4[tid] = tabPre;     // commit next step's table row

    // ---- combine wave stats (redundant per-thread) ----
    float M = mW[0];
    #pragma unroll
    for (int i=1;i<16;i++) M = fmaxf(M, mW[i]);
    double S = 0.0, base0 = 0.0;
    #pragma unroll
    for (int i=0;i<16;i++){
      if (i == wv) base0 = S;
      S += sW[i] * (double)expf(mW[i] - M);
    }
    double invS = 1.0 / S;
    double eW = (double)expf(m - M);
    double u0d = (double)u0;

    // ---- slot inversion + scatter ----
    int aPrev;
    {
      double cum0 = (base0 + excl*eW) * invS;
      aPrev = (int)floor(8192.0*cum0 - u0d);
      if (aPrev < -1) aPrev = -1;
    }
    #pragma unroll
    for (int k=0;k<8;k++){
      int i = tid*8 + k;
      double cum = (base0 + (excl + cp[k])*eW) * invS;
      int a;
      if (i == N_PART-1) a = N_PART-1;
      else {
        a = (int)floor(8192.0*cum - u0d);
        if (a > N_PART-1) a = N_PART-1;
      }
      if (a < aPrev) a = aPrev;             // enforce monotone under fp noise
      int st = aPrev + 1;
      if (st < N_PART) atomicMax(&idxA[st], i);
      for (int r = (st>>9)+1; (r<<9) <= a; ++r)
        atomicMax(&idxA[r<<9], i);          // wave-region anchors (<=15 iters)
      aPrev = a;
    }
    if (tid == 0)
      loss = ((loss + M) + (float)log(S)) - 9.010913347279289f;  // log(8192)
    __syncthreads();                        // B2

    // ---- wave max-scan over slots + gather ----
    int4 q0 = ((const int4*)idxA)[tid*2];
    int4 q1 = ((const int4*)idxA)[tid*2+1];
    int sl[8] = {q0.x,q0.y,q0.z,q0.w,q1.x,q1.y,q1.z,q1.w};
    int pm = sl[0];
    #pragma unroll
    for (int k=1;k<8;k++) pm = max(pm, sl[k]);
    int scn = pm;
    #pragma unroll
    for (int off=1; off<64; off<<=1){
      int o = __shfl_up(scn, (unsigned)off);
      if (lane >= off) scn = max(scn, o);
    }
    int ex = __shfl_up(scn, 1);
    if (lane == 0) ex = -1;                 // lane0 slot0 is a guaranteed anchor
    float sn[8];
    int run2 = ex;
    #pragma unroll
    for (int k=0;k<8;k++){
      run2 = max(run2, sl[k]);
      int idx = run2 < 0 ? 0 : run2;
      sn[k] = (float)socP[idx] * (1.0f/65535.0f);
    }
    if (strideP == 1){
      float4 a = {sn[0],sn[1],sn[2],sn[3]}, b = {sn[4],sn[5],sn[6],sn[7]};
      float4* dst = (float4*)(sHist + (size_t)t*strideT + tid*8);
      dst[0] = a; dst[1] = b;
    } else {
      #pragma unroll
      for (int k=0;k<8;k++) sHist[(size_t)t*strideT + (size_t)(tid*8+k)*strideP] = sn[k];
    }
    #pragma unroll
    for (int k=0;k<8;k++) soc[k] = sn[k];
    Iprev = It;
    nzA = nzA2; nzB = nzB2;
    __syncthreads();                        // B3 (WAR: socP gather vs next phase-1 writes)
  }
  if (tid == 0) lossOut[0] = loss;
}

// ---------------- kernel 6: (T,N) -> (N,T) transpose ----------------
__global__ void k_transpose(const float* __restrict__ vS, const float* __restrict__ sS,
                            float* __restrict__ outV, float* __restrict__ outS){
  __shared__ float tile[32][33];
  const float* src = blockIdx.z ? sS : vS;
  float* dst = blockIdx.z ? outS : outV;
  int t0 = blockIdx.x*32, n0 = blockIdx.y*32;
  int tx = threadIdx.x, ty = threadIdx.y;
  #pragma unroll
  for (int r=0;r<4;r++)
    tile[ty+8*r][tx] = src[(size_t)(t0+ty+8*r)*N_PART + n0 + tx];
  __syncthreads();
  #pragma unroll
  for (int r=0;r<4;r++)
    dst[(size_t)(n0+ty+8*r)*T_STEPS + t0 + tx] = tile[tx][ty+8*r];
}

extern "C" void kernel_launch(void* const* d_in, const int* in_sizes, int n_in,
                              void* d_out, int out_size, void* d_ws, size_t ws_size,
                              hipStream_t stream){
  const float* soc_init = (const float*)d_in[0];
  const float* current  = (const float*)d_in[1];
  const float* vmeas    = (const float*)d_in[2];
  const float* W1 = (const float*)d_in[3];
  const float* b1 = (const float*)d_in[4];
  const float* W2 = (const float*)d_in[5];
  const float* b2 = (const float*)d_in[6];
  const float* W3 = (const float*)d_in[7];
  const float* b3 = (const float*)d_in[8];
  const float* Ec = (const float*)d_in[9];

  float* outLoss = (float*)d_out;
  float* outV = outLoss + 1;
  float* outS = outV + (size_t)N_PART*T_STEPS;

  char* p = (char*)d_ws;
  auto carve = [&](size_t bytes)->char*{ char* r = p; p += (bytes + 255) & ~(size_t)255; return r; };
  uint32_t* knKeys  = (uint32_t*)carve((size_t)2*T_STEPS*4);
  float* u0Tab      = (float*)carve((size_t)T_STEPS*4);
  float* Zpart      = (float*)carve((size_t)4*M2TOT*4);
  float* Z2D        = (float*)carve((size_t)M2TOT*4);
  float* Gtab       = (float*)carve((size_t)T_STEPS*UKNOTS*4);
  float4* Tab4      = (float4*)carve((size_t)T_STEPS*128*16);
  float* noiseTab   = (float*)carve((size_t)N_PART*T_STEPS*4);
  float* vS         = (float*)carve((size_t)N_PART*T_STEPS*4);
  float* sS         = (float*)carve((size_t)N_PART*T_STEPS*4);
  bool useScratch   = ((size_t)(p - (char*)d_ws) <= ws_size);

  k_keys<<<dim3((T_STEPS+255)/256), dim3(256), 0, stream>>>(knKeys, u0Tab);
  k_noise<<<dim3(T_STEPS), dim3(256), 0, stream>>>(knKeys, noiseTab);
  k_gemm<<<dim3((M2TOT+63)/64, 4), dim3(256), 0, stream>>>(W1, b1, W2, b2, W3, Zpart);
  k_tabZ<<<dim3((M2TOT+255)/256), dim3(256), 0, stream>>>(Zpart, b3, Z2D);
  k_tabG<<<dim3((T_STEPS*UKNOTS+255)/256), dim3(256), 0, stream>>>(Z2D, current, Gtab);
  k_tab4<<<dim3((T_STEPS*128)/256), dim3(256), 0, stream>>>(Gtab, Tab4);

  if (useScratch){
    k_filter<<<dim3(1), dim3(1024), 0, stream>>>(soc_init, current, vmeas, Ec, Tab4, noiseTab,
                                                 u0Tab, vS, sS, (long)N_PART, 1L, outLoss);
    k_transpose<<<dim3(T_STEPS/32, N_PART/32, 2), dim3(32,8), 0, stream>>>(vS, sS, outV, outS);
  } else {
    k_filter<<<dim3(1), dim3(1024), 0, stream>>>(soc_init, current, vmeas, Ec, Tab4, noiseTab,
                                                 u0Tab, outV, outS, 1L, (long)T_STEPS, outLoss);
  }
}

// Round 3
// 10091.180 us; speedup vs baseline: 1.7983x; 1.2349x over previous
//
#include <hip/hip_runtime.h>
#include <stdint.h>
#include <math.h>

#define N_PART 8192
#define T_STEPS 1024
#define UKNOTS 130            // coarse u-knots k=0..129, u=k/128 (cubic source grid)
#define SIKNOTS 68            // sI-knots j=0..67, sI = SI_LO + j*SI_H
#define M2TOT (UKNOTS*SIKNOTS)
#define FKNOTS 2048           // fine linear grid in u
#define SI_LO 0.49375f
#define SI_H  0.00625f

// ---------------- Threefry-2x32 (exact JAX semantics) ----------------
__device__ __forceinline__ uint32_t rotl32(uint32_t x, int d){ return (x<<d)|(x>>(32-d)); }

__device__ __forceinline__ void tf2x32(uint32_t k0, uint32_t k1, uint32_t c0, uint32_t c1,
                                       uint32_t& o0, uint32_t& o1){
  uint32_t ks2 = k0 ^ k1 ^ 0x1BD11BDAu;
  uint32_t x0 = c0 + k0, x1 = c1 + k1;
  #define TFR(r) { x0 += x1; x1 = rotl32(x1, r); x1 ^= x0; }
  TFR(13) TFR(15) TFR(26) TFR(6)
  x0 += k1;  x1 += ks2 + 1u;
  TFR(17) TFR(29) TFR(16) TFR(24)
  x0 += ks2; x1 += k0 + 2u;
  TFR(13) TFR(15) TFR(26) TFR(6)
  x0 += k0;  x1 += k1 + 3u;
  TFR(17) TFR(29) TFR(16) TFR(24)
  x0 += k1;  x1 += ks2 + 4u;
  TFR(13) TFR(15) TFR(26) TFR(6)
  x0 += ks2; x1 += k0 + 5u;
  #undef TFR
  o0 = x0; o1 = x1;
}

__device__ __forceinline__ float erfinv_xla(float x){
  float w = -log1pf(-x*x);
  float p;
  if (w < 5.0f){
    w -= 2.5f;
    p = 2.81022636e-08f;
    p = fmaf(p, w, 3.43273939e-07f);
    p = fmaf(p, w, -3.5233877e-06f);
    p = fmaf(p, w, -4.39150654e-06f);
    p = fmaf(p, w, 0.00021858087f);
    p = fmaf(p, w, -0.00125372503f);
    p = fmaf(p, w, -0.00417768164f);
    p = fmaf(p, w, 0.246640727f);
    p = fmaf(p, w, 1.50140941f);
  } else {
    w = sqrtf(w) - 3.0f;
    p = -0.000200214257f;
    p = fmaf(p, w, 0.000100950558f);
    p = fmaf(p, w, 0.00134934322f);
    p = fmaf(p, w, -0.00367342844f);
    p = fmaf(p, w, 0.00573950773f);
    p = fmaf(p, w, -0.0076224613f);
    p = fmaf(p, w, 0.00943887047f);
    p = fmaf(p, w, 1.00167406f);
    p = fmaf(p, w, 2.83297682f);
  }
  return p * x;
}

// ---------------- kernel 1: per-step keys + u0 ----------------
__global__ void k_keys(uint32_t* __restrict__ knKeys, float* __restrict__ u0Tab){
  int t = blockIdx.x*blockDim.x + threadIdx.x;
  if (t >= T_STEPS) return;
  uint32_t kA0,kA1,kB0,kB1;
  tf2x32(0u,42u, 0u,0u, kA0,kA1);
  tf2x32(0u,42u, 0u,1u, kB0,kB1);
  auto splitElem = [&](uint32_t kk0, uint32_t kk1, int idx)->uint32_t{
    uint32_t o0,o1;
    if (idx < T_STEPS){ tf2x32(kk0,kk1,(uint32_t)idx,(uint32_t)(T_STEPS+idx),o0,o1); return o0; }
    int i = idx - T_STEPS;
    tf2x32(kk0,kk1,(uint32_t)i,(uint32_t)(T_STEPS+i),o0,o1); return o1;
  };
  uint32_t n0 = splitElem(kA0,kA1, 2*t);
  uint32_t n1 = splitElem(kA0,kA1, 2*t+1);
  uint32_t r0 = splitElem(kB0,kB1, 2*t);
  uint32_t r1 = splitElem(kB0,kB1, 2*t+1);
  knKeys[2*t] = n0; knKeys[2*t+1] = n1;
  uint32_t o0,o1; tf2x32(r0,r1,0u,0u,o0,o1);
  u0Tab[t] = __uint_as_float((o0>>9) | 0x3f800000u) - 1.0f;
}

// ---------------- kernel 2: noise table ----------------
__global__ void k_noise(const uint32_t* __restrict__ knKeys, float* __restrict__ noiseTab){
  int t = blockIdx.x;
  uint32_t k0 = knKeys[2*t], k1 = knKeys[2*t+1];
  const int half = N_PART/2;
  const float lo = -0.99999994f;
  for (int i = threadIdx.x; i < half; i += blockDim.x){
    uint32_t o0,o1; tf2x32(k0,k1,(uint32_t)i,(uint32_t)(half+i),o0,o1);
    float ua = __uint_as_float((o0>>9)|0x3f800000u) - 1.0f;
    float ub = __uint_as_float((o1>>9)|0x3f800000u) - 1.0f;
    float va = fmaxf(lo, ua*2.0f + lo);
    float vb = fmaxf(lo, ub*2.0f + lo);
    float na = 1.4142135623730951f * erfinv_xla(va);
    float nb = 1.4142135623730951f * erfinv_xla(vb);
    noiseTab[(size_t)t*N_PART + i]        = 0.005f * na;
    noiseTab[(size_t)t*N_PART + half + i] = 0.005f * nb;
  }
}

// ---------------- kernel 3: (u, sI)-grid MLP GEMM ----------------
__global__ __launch_bounds__(256) void k_gemm(
    const float* __restrict__ W1, const float* __restrict__ b1,
    const float* __restrict__ W2, const float* __restrict__ b2,
    const float* __restrict__ W3, float* __restrict__ Zpart)
{
  __shared__ float sA[32][64];
  __shared__ float sB[32][129];
  __shared__ float sSoc[64], sSI[64];
  __shared__ float sRed[64][17];

  const int tid = threadIdx.x;
  const int m0 = blockIdx.x * 64;
  const int n0 = blockIdx.y * 128;

  if (tid < 64){
    int r = m0 + tid; if (r >= M2TOT) r = M2TOT-1;
    int k = r / SIKNOTS;
    int j = r - k*SIKNOTS;
    float u = (float)k * (1.0f/128.0f);
    sSoc[tid] = u*u;
    sSI[tid]  = SI_LO + SI_H * (float)j;
  }
  __syncthreads();

  const int tx = tid & 15;
  const int ty = tid >> 4;
  float acc[4][8];
  #pragma unroll
  for (int i=0;i<4;i++)
    #pragma unroll
    for (int q=0;q<8;q++) acc[i][q] = 0.0f;

  for (int kc = 0; kc < 1024; kc += 32){
    {
      int base = tid*8;
      int jj = base >> 6;
      int mm = base & 63;
      int j = kc + jj;
      float w0 = W1[2*j], w1v = W1[2*j+1], bb = b1[j];
      #pragma unroll
      for (int e=0;e<8;e++){
        int m = mm + e;
        float pre = sSoc[m]*w0 + sSI[m]*w1v + bb;
        sA[jj][m] = 1.0f/(1.0f + expf(-pre));
      }
    }
    {
      int nl = tid & 127;
      int h  = tid >> 7;
      const float* src = W2 + (size_t)(n0 + nl)*1024 + kc + h*16;
      float4 v0 = *(const float4*)(src+0);
      float4 v1 = *(const float4*)(src+4);
      float4 v2 = *(const float4*)(src+8);
      float4 v3 = *(const float4*)(src+12);
      int kb = h*16;
      sB[kb+ 0][nl]=v0.x; sB[kb+ 1][nl]=v0.y; sB[kb+ 2][nl]=v0.z; sB[kb+ 3][nl]=v0.w;
      sB[kb+ 4][nl]=v1.x; sB[kb+ 5][nl]=v1.y; sB[kb+ 6][nl]=v1.z; sB[kb+ 7][nl]=v1.w;
      sB[kb+ 8][nl]=v2.x; sB[kb+ 9][nl]=v2.y; sB[kb+10][nl]=v2.z; sB[kb+11][nl]=v2.w;
      sB[kb+12][nl]=v3.x; sB[kb+13][nl]=v3.y; sB[kb+14][nl]=v3.z; sB[kb+15][nl]=v3.w;
    }
    __syncthreads();
    #pragma unroll
    for (int kk=0;kk<32;kk++){
      float a_[4], b_[8];
      #pragma unroll
      for (int i=0;i<4;i++) a_[i] = sA[kk][ty*4+i];
      #pragma unroll
      for (int q=0;q<8;q++) b_[q] = sB[kk][tx*8+q];
      #pragma unroll
      for (int i=0;i<4;i++)
        #pragma unroll
        for (int q=0;q<8;q++) acc[i][q] = fmaf(a_[i], b_[q], acc[i][q]);
    }
    __syncthreads();
  }
  float part[4] = {0.f,0.f,0.f,0.f};
  #pragma unroll
  for (int q=0;q<8;q++){
    int n = n0 + tx*8 + q;
    float bb = b2[n], w3 = W3[n];
    #pragma unroll
    for (int i=0;i<4;i++){
      float h = 1.0f/(1.0f + expf(-(acc[i][q] + bb)));
      part[i] = fmaf(w3, h, part[i]);
    }
  }
  #pragma unroll
  for (int i=0;i<4;i++) sRed[ty*4+i][tx] = part[i];
  __syncthreads();
  if (tid < 64){
    int r = m0 + tid;
    if (r < M2TOT){
      float s = 0.0f;
      #pragma unroll
      for (int x=0;x<16;x++) s += sRed[tid][x];
      Zpart[(size_t)blockIdx.y*M2TOT + r] = s;
    }
  }
}

// ---------------- kernel 4a: combine Z parts ----------------
__global__ void k_tabZ(const float* __restrict__ Zpart, const float* __restrict__ b3,
                       float* __restrict__ Z2D){
  int r = blockIdx.x*blockDim.x + threadIdx.x;
  if (r >= M2TOT) return;
  Z2D[r] = ((Zpart[r] + Zpart[M2TOT+r]) + Zpart[2*M2TOT+r]) + Zpart[3*M2TOT+r] + b3[0];
}

// ---------------- kernel 4b: per-(t,k) sI-interp + voc -> coarse G table ----------------
__global__ void k_tabG(const float* __restrict__ Z2D, const float* __restrict__ current,
                       float* __restrict__ Gtab){
  int m = blockIdx.x*blockDim.x + threadIdx.x;
  if (m >= T_STEPS*UKNOTS) return;
  int t = m / UKNOTS;
  int k = m - t*UKNOTS;
  float It = current[t];
  float sI = (It + 2.0f) * 0.25f;
  float x = (sI - SI_LO) * (1.0f/SI_H);
  int c = (int)x; if (c < 1) c = 1; if (c > 65) c = 65;
  float xi = x - (float)c;
  const float* zp = Z2D + k*SIKNOTS + (c-1);
  float y0 = zp[0], y1 = zp[1], y2 = zp[2], y3 = zp[3];
  float xm1 = xi - 1.0f, xm2 = xi - 2.0f, xp1 = xi + 1.0f;
  float w0 = -(1.0f/6.0f) * xi  * xm1 * xm2;
  float w1 =  0.5f        * xp1 * xm1 * xm2;
  float w2 = -0.5f        * xi  * xp1 * xm2;
  float w3 =  (1.0f/6.0f) * xi  * xp1 * xm1;
  float z = ((w0*y0 + w1*y1) + w2*y2) + w3*y3;
  double u = (double)k / 128.0;
  double s = u*u;
  const double vL=-1.59614486, v0=4.13646328, gam=0.63726463, alp=1.40174122, bet=2.54478965;
  double voc = vL + (v0-vL)*exp(gam*(s-1.0)) + alp*vL*(s-1.0)
             + (1.0-alp)*vL*(exp(-bet) - exp(-bet*sqrt(s)));
  Gtab[m] = (float)voc - It*z;
}

// ---------------- kernel 4c: expand coarse cubic -> fine linear pair table ----------------
// Tab2[t][c] = (V(u=c/2048), V(u=(c+1)/2048)), c in [0,2048)
__device__ __forceinline__ float cubicEval(const float* __restrict__ g, int cf){
  float x = (float)cf * (1.0f/16.0f);      // u*128 = cf*128/2048
  int cc = (int)x; if (cc > 127) cc = 127;
  float xi = x - (float)cc;
  float y0 = (cc == 0) ? g[1] : g[cc-1];   // even mirror in u
  float y1 = g[cc], y2 = g[cc+1], y3 = g[cc+2];
  float xm1 = xi - 1.0f, xm2 = xi - 2.0f, xp1 = xi + 1.0f;
  float w0 = -(1.0f/6.0f) * xi  * xm1 * xm2;
  float w1 =  0.5f        * xp1 * xm1 * xm2;
  float w2 = -0.5f        * xi  * xp1 * xm2;
  float w3 =  (1.0f/6.0f) * xi  * xp1 * xm1;
  return ((w0*y0 + w1*y1) + w2*y2) + w3*y3;
}
__global__ void k_tabFine(const float* __restrict__ Gtab, float2* __restrict__ Tab2){
  int m = blockIdx.x*blockDim.x + threadIdx.x;
  if (m >= T_STEPS*FKNOTS) return;
  int t = m >> 11;
  int c = m & (FKNOTS-1);
  const float* g = Gtab + t*UKNOTS;
  Tab2[m] = make_float2(cubicEval(g, c), cubicEval(g, c+1));
}

// linear interp via fine pair table: one ds_read_b64
__device__ __forceinline__ float interpL(const float2* __restrict__ tab, float s){
  float x = sqrtf(s) * 2048.0f;
  int c = (int)x; if (c > 2047) c = 2047;
  float xi = x - (float)c;
  float2 Y = tab[c];
  return fmaf(xi, Y.y - Y.x, Y.x);
}

// ---------------- kernel 5: sequential particle filter (single block, 1024 thr) ----------------
__global__ __launch_bounds__(1024) void k_filter(
    const float* __restrict__ soc_init, const float* __restrict__ current,
    const float* __restrict__ vmeas,   const float* __restrict__ Ecrit,
    const float2* __restrict__ Tab2,   const float* __restrict__ noiseTab,
    const float* __restrict__ u0Tab,   float* __restrict__ socNew,
    float* __restrict__ vHist, float* __restrict__ sHist,
    long strideT, long strideP, float* __restrict__ lossOut)
{
  __shared__ __align__(16) int    idxA[N_PART];        // 32 KiB
  __shared__ __align__(16) float2 tabL[FKNOTS];        // 16 KiB
  __shared__ float mW[16];
  __shared__ float sWv[16];

  const int tid = threadIdx.x;
  const int lane = tid & 63;
  const int wv = tid >> 6;
  const float ec = Ecrit[0];

  // prologue: fine table row 0 + noise row 0
  ((float4*)tabL)[tid] = ((const float4*)Tab2)[tid];
  const float4* nzp = (const float4*)noiseTab + tid*2;
  float4 nzA = nzp[0], nzB = nzp[1];
  float soc[8], V[8];
  __syncthreads();
  #pragma unroll
  for (int k=0;k<8;k++){
    float s = soc_init[tid*8+k];
    soc[k] = s;
    V[k] = interpL(tabL, s);
  }
  float loss = 0.0f;
  float Iprev = current[0];

  for (int t=0; t<T_STEPS; t++){
    // ---- phase 1: prefetch next-step tables ----
    int tn = (t+1 < T_STEPS) ? t+1 : t;
    float4 tabPre = ((const float4*)(Tab2 + (size_t)tn*FKNOTS))[tid];
    const float4* nzn = (const float4*)(noiseTab + (size_t)tn*N_PART) + tid*2;
    float4 nzA2 = nzn[0], nzB2 = nzn[1];

    float It = current[t];
    float vm = vmeas[t];
    float u0 = u0Tab[t];
    float nz[8] = {nzA.x,nzA.y,nzA.z,nzA.w,nzB.x,nzB.y,nzB.z,nzB.w};

    // propagate + measure
    float sp[8], lw[8];
    float m = -INFINITY;
    #pragma unroll
    for (int k=0;k<8;k++){
      float s = soc[k];
      float tmp = Iprev * V[k];
      tmp = tmp / 26267.160775850585f;
      tmp = tmp * ec;
      s = s - tmp;
      s = s + nz[k];
      s = (s > 1.0f) ? 1.0f : ((s < 0.0f) ? 1e-10f : s);
      sp[k] = s;
      float Vn = interpL(tabL, s);
      V[k] = Vn;
      float d = (Vn - vm) * 100.0f;
      lw[k] = 3.6862316527834183f - 0.5f*(d*d);
      m = fmaxf(m, lw[k]);
    }
    { // exact f32 propagated state -> global scratch (visible after B1's vmcnt drain)
      float4 a = {sp[0],sp[1],sp[2],sp[3]}, b = {sp[4],sp[5],sp[6],sp[7]};
      float4* dst = (float4*)(socNew + tid*8);
      dst[0] = a; dst[1] = b;
    }
    if (strideP == 1){
      float4 a = {V[0],V[1],V[2],V[3]}, b = {V[4],V[5],V[6],V[7]};
      float4* dst = (float4*)(vHist + (size_t)t*strideT + tid*8);
      dst[0] = a; dst[1] = b;
    } else {
      #pragma unroll
      for (int k=0;k<8;k++) vHist[(size_t)t*strideT + (size_t)(tid*8+k)*strideP] = V[k];
    }
    { int4 mm1 = {-1,-1,-1,-1}; ((int4*)idxA)[tid*2] = mm1; ((int4*)idxA)[tid*2+1] = mm1; }

    // wave max + f32 prefix sums
    #pragma unroll
    for (int off=1; off<64; off<<=1) m = fmaxf(m, __shfl_xor(m, off));
    float run = 0.0f, cp[8];
    #pragma unroll
    for (int k=0;k<8;k++){
      float e = __expf(lw[k] - m);
      run += e;
      cp[k] = run;
    }
    float sc = run;
    #pragma unroll
    for (int off=1; off<64; off<<=1){
      float o = __shfl_up(sc, (unsigned)off);
      if (lane >= off) sc += o;
    }
    float excl = sc - run;
    if (lane == 63){ mW[wv] = m; sWv[wv] = sc; }
    __syncthreads();                        // B1

    ((float4*)tabL)[tid] = tabPre;          // commit next step's table row

    // ---- combine wave stats: lanes 0..15 of every wave (no extra barrier) ----
    float baseV = 0.0f, scaleV = 0.0f;
    if (lane < 16){
      float mv = mW[lane];
      float M2 = mv;
      #pragma unroll
      for (int off=1; off<16; off<<=1) M2 = fmaxf(M2, __shfl_xor(M2, off));
      float ew = __expf(mv - M2);
      float term = sWv[lane] * ew;
      float pf = term;
      #pragma unroll
      for (int off=1; off<16; off<<=1){
        float o = __shfl_up(pf, (unsigned)off);
        if (lane >= off) pf += o;
      }
      float Sv = __shfl(pf, 15);
      float invS = 1.0f / Sv;
      baseV  = (pf - term) * invS;
      scaleV = ew * invS;
      if (tid == 0)
        loss = ((loss + M2) + logf(Sv)) - 9.010913347279288f;   // log(8192)
    }
    float b0  = __shfl(baseV, wv);
    float scl = __shfl(scaleV, wv);

    // ---- slot inversion + scatter (all f32) ----
    float scl8 = scl * 8192.0f;
    float bth  = fmaf(excl, scl8, fmaf(b0, 8192.0f, -u0));
    int aPrev = (int)floorf(bth);
    if (aPrev < -1) aPrev = -1;
    #pragma unroll
    for (int k=0;k<8;k++){
      int i = tid*8 + k;
      int a;
      if (i == N_PART-1) a = N_PART-1;
      else {
        a = (int)floorf(fmaf(cp[k], scl8, bth));
        if (a > N_PART-1) a = N_PART-1;
      }
      if (a < aPrev) a = aPrev;
      int st = aPrev + 1;
      if (st < N_PART) atomicMax(&idxA[st], i);
      for (int r = (st>>9)+1; (r<<9) <= a; ++r)
        atomicMax(&idxA[r<<9], i);          // 512-region anchors
      aPrev = a;
    }
    __syncthreads();                        // B2

    // ---- wave max-scan over slots + global gather ----
    int4 q0 = ((const int4*)idxA)[tid*2];
    int4 q1 = ((const int4*)idxA)[tid*2+1];
    int sl[8] = {q0.x,q0.y,q0.z,q0.w,q1.x,q1.y,q1.z,q1.w};
    int pm = sl[0];
    #pragma unroll
    for (int k=1;k<8;k++) pm = max(pm, sl[k]);
    int scn = pm;
    #pragma unroll
    for (int off=1; off<64; off<<=1){
      int o = __shfl_up(scn, (unsigned)off);
      if (lane >= off) scn = max(scn, o);
    }
    int ex = __shfl_up(scn, 1);
    if (lane == 0) ex = -1;                 // lane0's slot0 anchor is guaranteed
    float sn[8];
    int run2 = ex;
    #pragma unroll
    for (int k=0;k<8;k++){
      run2 = max(run2, sl[k]);
      int idx = run2 < 0 ? 0 : run2;
      sn[k] = socNew[idx];                  // exact f32 gather from global (L1/L2)
    }
    if (strideP == 1){
      float4 a = {sn[0],sn[1],sn[2],sn[3]}, b = {sn[4],sn[5],sn[6],sn[7]};
      float4* dst = (float4*)(sHist + (size_t)t*strideT + tid*8);
      dst[0] = a; dst[1] = b;
    } else {
      #pragma unroll
      for (int k=0;k<8;k++) sHist[(size_t)t*strideT + (size_t)(tid*8+k)*strideP] = sn[k];
    }
    #pragma unroll
    for (int k=0;k<8;k++) soc[k] = sn[k];
    Iprev = It;
    nzA = nzA2; nzB = nzB2;
    __syncthreads();                        // B3 (WAR: socNew/idxA next-step writes)
  }
  if (tid == 0) lossOut[0] = loss;
}

// ---------------- kernel 6: (T,N) -> (N,T) transpose ----------------
__global__ void k_transpose(const float* __restrict__ vS, const float* __restrict__ sS,
                            float* __restrict__ outV, float* __restrict__ outS){
  __shared__ float tile[32][33];
  const float* src = blockIdx.z ? sS : vS;
  float* dst = blockIdx.z ? outS : outV;
  int t0 = blockIdx.x*32, n0 = blockIdx.y*32;
  int tx = threadIdx.x, ty = threadIdx.y;
  #pragma unroll
  for (int r=0;r<4;r++)
    tile[ty+8*r][tx] = src[(size_t)(t0+ty+8*r)*N_PART + n0 + tx];
  __syncthreads();
  #pragma unroll
  for (int r=0;r<4;r++)
    dst[(size_t)(n0+ty+8*r)*T_STEPS + t0 + tx] = tile[tx][ty+8*r];
}

extern "C" void kernel_launch(void* const* d_in, const int* in_sizes, int n_in,
                              void* d_out, int out_size, void* d_ws, size_t ws_size,
                              hipStream_t stream){
  const float* soc_init = (const float*)d_in[0];
  const float* current  = (const float*)d_in[1];
  const float* vmeas    = (const float*)d_in[2];
  const float* W1 = (const float*)d_in[3];
  const float* b1 = (const float*)d_in[4];
  const float* W2 = (const float*)d_in[5];
  const float* b2 = (const float*)d_in[6];
  const float* W3 = (const float*)d_in[7];
  const float* b3 = (const float*)d_in[8];
  const float* Ec = (const float*)d_in[9];

  float* outLoss = (float*)d_out;
  float* outV = outLoss + 1;
  float* outS = outV + (size_t)N_PART*T_STEPS;

  char* p = (char*)d_ws;
  auto carve = [&](size_t bytes)->char*{ char* r = p; p += (bytes + 255) & ~(size_t)255; return r; };
  // mandatory scratch first
  uint32_t* knKeys  = (uint32_t*)carve((size_t)2*T_STEPS*4);
  float* u0Tab      = (float*)carve((size_t)T_STEPS*4);
  float* socNew     = (float*)carve((size_t)N_PART*4);
  float* Zpart      = (float*)carve((size_t)4*M2TOT*4);
  float* Z2D        = (float*)carve((size_t)M2TOT*4);
  float* Gtab       = (float*)carve((size_t)T_STEPS*UKNOTS*4);
  float2* Tab2      = (float2*)carve((size_t)T_STEPS*FKNOTS*8);
  float* noiseTab   = (float*)carve((size_t)N_PART*T_STEPS*4);
  // optional (T,N) staging for coalesced hist writes
  float* vS         = (float*)carve((size_t)N_PART*T_STEPS*4);
  float* sS         = (float*)carve((size_t)N_PART*T_STEPS*4);
  bool useScratch   = ((size_t)(p - (char*)d_ws) <= ws_size);

  k_keys<<<dim3((T_STEPS+255)/256), dim3(256), 0, stream>>>(knKeys, u0Tab);
  k_noise<<<dim3(T_STEPS), dim3(256), 0, stream>>>(knKeys, noiseTab);
  k_gemm<<<dim3((M2TOT+63)/64, 4), dim3(256), 0, stream>>>(W1, b1, W2, b2, W3, Zpart);
  k_tabZ<<<dim3((M2TOT+255)/256), dim3(256), 0, stream>>>(Zpart, b3, Z2D);
  k_tabG<<<dim3((T_STEPS*UKNOTS+255)/256), dim3(256), 0, stream>>>(Z2D, current, Gtab);
  k_tabFine<<<dim3((T_STEPS*FKNOTS)/256), dim3(256), 0, stream>>>(Gtab, Tab2);

  if (useScratch){
    k_filter<<<dim3(1), dim3(1024), 0, stream>>>(soc_init, current, vmeas, Ec, Tab2, noiseTab,
                                                 u0Tab, socNew, vS, sS, (long)N_PART, 1L, outLoss);
    k_transpose<<<dim3(T_STEPS/32, N_PART/32, 2), dim3(32,8), 0, stream>>>(vS, sS, outV, outS);
  } else {
    k_filter<<<dim3(1), dim3(1024), 0, stream>>>(soc_init, current, vmeas, Ec, Tab2, noiseTab,
                                                 u0Tab, socNew, outV, outS, 1L, (long)T_STEPS, outLoss);
  }
}

// Round 4
// 9220.419 us; speedup vs baseline: 1.9681x; 1.0944x over previous
//
#include <hip/hip_runtime.h>
#include <stdint.h>
#include <math.h>

#define N_PART 8192
#define T_STEPS 1024
#define UKNOTS 130            // coarse u-knots k=0..129, u=k/128 (cubic source grid)
#define SIKNOTS 68            // sI-knots j=0..67, sI = SI_LO + j*SI_H
#define M2TOT (UKNOTS*SIKNOTS)
#define FKN 2049              // fine linear grid in u: entries c=0..2048, u=c/2048
#define SI_LO 0.49375f
#define SI_H  0.00625f
#define LOGNU 3.6862316527834183f
#define LOG8192 9.010913347279288f
#define DD2LW 5000.0f                 // lw = LOGNU - 5000*dd, dd=(V-vm)^2
#define DD2E  7213.4752044448170f     // 5000*log2(e)

// ---------------- Threefry-2x32 (exact JAX semantics) ----------------
__device__ __forceinline__ uint32_t rotl32(uint32_t x, int d){ return (x<<d)|(x>>(32-d)); }

__device__ __forceinline__ void tf2x32(uint32_t k0, uint32_t k1, uint32_t c0, uint32_t c1,
                                       uint32_t& o0, uint32_t& o1){
  uint32_t ks2 = k0 ^ k1 ^ 0x1BD11BDAu;
  uint32_t x0 = c0 + k0, x1 = c1 + k1;
  #define TFR(r) { x0 += x1; x1 = rotl32(x1, r); x1 ^= x0; }
  TFR(13) TFR(15) TFR(26) TFR(6)
  x0 += k1;  x1 += ks2 + 1u;
  TFR(17) TFR(29) TFR(16) TFR(24)
  x0 += ks2; x1 += k0 + 2u;
  TFR(13) TFR(15) TFR(26) TFR(6)
  x0 += k0;  x1 += k1 + 3u;
  TFR(17) TFR(29) TFR(16) TFR(24)
  x0 += k1;  x1 += ks2 + 4u;
  TFR(13) TFR(15) TFR(26) TFR(6)
  x0 += ks2; x1 += k0 + 5u;
  #undef TFR
  o0 = x0; o1 = x1;
}

__device__ __forceinline__ float erfinv_xla(float x){
  float w = -log1pf(-x*x);
  float p;
  if (w < 5.0f){
    w -= 2.5f;
    p = 2.81022636e-08f;
    p = fmaf(p, w, 3.43273939e-07f);
    p = fmaf(p, w, -3.5233877e-06f);
    p = fmaf(p, w, -4.39150654e-06f);
    p = fmaf(p, w, 0.00021858087f);
    p = fmaf(p, w, -0.00125372503f);
    p = fmaf(p, w, -0.00417768164f);
    p = fmaf(p, w, 0.246640727f);
    p = fmaf(p, w, 1.50140941f);
  } else {
    w = sqrtf(w) - 3.0f;
    p = -0.000200214257f;
    p = fmaf(p, w, 0.000100950558f);
    p = fmaf(p, w, 0.00134934322f);
    p = fmaf(p, w, -0.00367342844f);
    p = fmaf(p, w, 0.00573950773f);
    p = fmaf(p, w, -0.0076224613f);
    p = fmaf(p, w, 0.00943887047f);
    p = fmaf(p, w, 1.00167406f);
    p = fmaf(p, w, 2.83297682f);
  }
  return p * x;
}

// ---------------- kernel 1: per-step keys + u0 ----------------
__global__ void k_keys(uint32_t* __restrict__ knKeys, float* __restrict__ u0Tab){
  int t = blockIdx.x*blockDim.x + threadIdx.x;
  if (t >= T_STEPS) return;
  uint32_t kA0,kA1,kB0,kB1;
  tf2x32(0u,42u, 0u,0u, kA0,kA1);
  tf2x32(0u,42u, 0u,1u, kB0,kB1);
  auto splitElem = [&](uint32_t kk0, uint32_t kk1, int idx)->uint32_t{
    uint32_t o0,o1;
    if (idx < T_STEPS){ tf2x32(kk0,kk1,(uint32_t)idx,(uint32_t)(T_STEPS+idx),o0,o1); return o0; }
    int i = idx - T_STEPS;
    tf2x32(kk0,kk1,(uint32_t)i,(uint32_t)(T_STEPS+i),o0,o1); return o1;
  };
  uint32_t n0 = splitElem(kA0,kA1, 2*t);
  uint32_t n1 = splitElem(kA0,kA1, 2*t+1);
  uint32_t r0 = splitElem(kB0,kB1, 2*t);
  uint32_t r1 = splitElem(kB0,kB1, 2*t+1);
  knKeys[2*t] = n0; knKeys[2*t+1] = n1;
  uint32_t o0,o1; tf2x32(r0,r1,0u,0u,o0,o1);
  u0Tab[t] = __uint_as_float((o0>>9) | 0x3f800000u) - 1.0f;
}

// ---------------- kernel 2: noise table ----------------
__global__ void k_noise(const uint32_t* __restrict__ knKeys, float* __restrict__ noiseTab){
  int t = blockIdx.x;
  uint32_t k0 = knKeys[2*t], k1 = knKeys[2*t+1];
  const int half = N_PART/2;
  const float lo = -0.99999994f;
  for (int i = threadIdx.x; i < half; i += blockDim.x){
    uint32_t o0,o1; tf2x32(k0,k1,(uint32_t)i,(uint32_t)(half+i),o0,o1);
    float ua = __uint_as_float((o0>>9)|0x3f800000u) - 1.0f;
    float ub = __uint_as_float((o1>>9)|0x3f800000u) - 1.0f;
    float va = fmaxf(lo, ua*2.0f + lo);
    float vb = fmaxf(lo, ub*2.0f + lo);
    float na = 1.4142135623730951f * erfinv_xla(va);
    float nb = 1.4142135623730951f * erfinv_xla(vb);
    noiseTab[(size_t)t*N_PART + i]        = 0.005f * na;
    noiseTab[(size_t)t*N_PART + half + i] = 0.005f * nb;
  }
}

// ---------------- kernel 3: (u, sI)-grid MLP GEMM ----------------
__global__ __launch_bounds__(256) void k_gemm(
    const float* __restrict__ W1, const float* __restrict__ b1,
    const float* __restrict__ W2, const float* __restrict__ b2,
    const float* __restrict__ W3, float* __restrict__ Zpart)
{
  __shared__ float sA[32][64];
  __shared__ float sB[32][129];
  __shared__ float sSoc[64], sSI[64];
  __shared__ float sRed[64][17];

  const int tid = threadIdx.x;
  const int m0 = blockIdx.x * 64;
  const int n0 = blockIdx.y * 128;

  if (tid < 64){
    int r = m0 + tid; if (r >= M2TOT) r = M2TOT-1;
    int k = r / SIKNOTS;
    int j = r - k*SIKNOTS;
    float u = (float)k * (1.0f/128.0f);
    sSoc[tid] = u*u;
    sSI[tid]  = SI_LO + SI_H * (float)j;
  }
  __syncthreads();

  const int tx = tid & 15;
  const int ty = tid >> 4;
  float acc[4][8];
  #pragma unroll
  for (int i=0;i<4;i++)
    #pragma unroll
    for (int q=0;q<8;q++) acc[i][q] = 0.0f;

  for (int kc = 0; kc < 1024; kc += 32){
    {
      int base = tid*8;
      int jj = base >> 6;
      int mm = base & 63;
      int j = kc + jj;
      float w0 = W1[2*j], w1v = W1[2*j+1], bb = b1[j];
      #pragma unroll
      for (int e=0;e<8;e++){
        int m = mm + e;
        float pre = sSoc[m]*w0 + sSI[m]*w1v + bb;
        sA[jj][m] = 1.0f/(1.0f + expf(-pre));
      }
    }
    {
      int nl = tid & 127;
      int h  = tid >> 7;
      const float* src = W2 + (size_t)(n0 + nl)*1024 + kc + h*16;
      float4 v0 = *(const float4*)(src+0);
      float4 v1 = *(const float4*)(src+4);
      float4 v2 = *(const float4*)(src+8);
      float4 v3 = *(const float4*)(src+12);
      int kb = h*16;
      sB[kb+ 0][nl]=v0.x; sB[kb+ 1][nl]=v0.y; sB[kb+ 2][nl]=v0.z; sB[kb+ 3][nl]=v0.w;
      sB[kb+ 4][nl]=v1.x; sB[kb+ 5][nl]=v1.y; sB[kb+ 6][nl]=v1.z; sB[kb+ 7][nl]=v1.w;
      sB[kb+ 8][nl]=v2.x; sB[kb+ 9][nl]=v2.y; sB[kb+10][nl]=v2.z; sB[kb+11][nl]=v2.w;
      sB[kb+12][nl]=v3.x; sB[kb+13][nl]=v3.y; sB[kb+14][nl]=v3.z; sB[kb+15][nl]=v3.w;
    }
    __syncthreads();
    #pragma unroll
    for (int kk=0;kk<32;kk++){
      float a_[4], b_[8];
      #pragma unroll
      for (int i=0;i<4;i++) a_[i] = sA[kk][ty*4+i];
      #pragma unroll
      for (int q=0;q<8;q++) b_[q] = sB[kk][tx*8+q];
      #pragma unroll
      for (int i=0;i<4;i++)
        #pragma unroll
        for (int q=0;q<8;q++) acc[i][q] = fmaf(a_[i], b_[q], acc[i][q]);
    }
    __syncthreads();
  }
  float part[4] = {0.f,0.f,0.f,0.f};
  #pragma unroll
  for (int q=0;q<8;q++){
    int n = n0 + tx*8 + q;
    float bb = b2[n], w3 = W3[n];
    #pragma unroll
    for (int i=0;i<4;i++){
      float h = 1.0f/(1.0f + expf(-(acc[i][q] + bb)));
      part[i] = fmaf(w3, h, part[i]);
    }
  }
  #pragma unroll
  for (int i=0;i<4;i++) sRed[ty*4+i][tx] = part[i];
  __syncthreads();
  if (tid < 64){
    int r = m0 + tid;
    if (r < M2TOT){
      float s = 0.0f;
      #pragma unroll
      for (int x=0;x<16;x++) s += sRed[tid][x];
      Zpart[(size_t)blockIdx.y*M2TOT + r] = s;
    }
  }
}

// ---------------- kernel 4a: combine Z parts ----------------
__global__ void k_tabZ(const float* __restrict__ Zpart, const float* __restrict__ b3,
                       float* __restrict__ Z2D){
  int r = blockIdx.x*blockDim.x + threadIdx.x;
  if (r >= M2TOT) return;
  Z2D[r] = ((Zpart[r] + Zpart[M2TOT+r]) + Zpart[2*M2TOT+r]) + Zpart[3*M2TOT+r] + b3[0];
}

// ---------------- kernel 4b: per-(t,k) sI-interp + voc -> coarse G table ----------------
__global__ void k_tabG(const float* __restrict__ Z2D, const float* __restrict__ current,
                       float* __restrict__ Gtab){
  int m = blockIdx.x*blockDim.x + threadIdx.x;
  if (m >= T_STEPS*UKNOTS) return;
  int t = m / UKNOTS;
  int k = m - t*UKNOTS;
  float It = current[t];
  float sI = (It + 2.0f) * 0.25f;
  float x = (sI - SI_LO) * (1.0f/SI_H);
  int c = (int)x; if (c < 1) c = 1; if (c > 65) c = 65;
  float xi = x - (float)c;
  const float* zp = Z2D + k*SIKNOTS + (c-1);
  float y0 = zp[0], y1 = zp[1], y2 = zp[2], y3 = zp[3];
  float xm1 = xi - 1.0f, xm2 = xi - 2.0f, xp1 = xi + 1.0f;
  float w0 = -(1.0f/6.0f) * xi  * xm1 * xm2;
  float w1 =  0.5f        * xp1 * xm1 * xm2;
  float w2 = -0.5f        * xi  * xp1 * xm2;
  float w3 =  (1.0f/6.0f) * xi  * xp1 * xm1;
  float z = ((w0*y0 + w1*y1) + w2*y2) + w3*y3;
  double u = (double)k / 128.0;
  double s = u*u;
  const double vL=-1.59614486, v0=4.13646328, gam=0.63726463, alp=1.40174122, bet=2.54478965;
  double voc = vL + (v0-vL)*exp(gam*(s-1.0)) + alp*vL*(s-1.0)
             + (1.0-alp)*vL*(exp(-bet) - exp(-bet*sqrt(s)));
  Gtab[m] = (float)voc - It*z;
}

// ---------------- kernel 4c: coarse cubic -> fine scalar table TabF[t][c], c in [0,2048] ----------------
__device__ __forceinline__ float cubicEval(const float* __restrict__ g, int cf){
  float x = (float)cf * (1.0f/16.0f);
  int cc = (int)x; if (cc > 127) cc = 127;
  float xi = x - (float)cc;
  float y0 = (cc == 0) ? g[1] : g[cc-1];   // even mirror in u
  float y1 = g[cc], y2 = g[cc+1], y3 = g[cc+2];
  float xm1 = xi - 1.0f, xm2 = xi - 2.0f, xp1 = xi + 1.0f;
  float w0 = -(1.0f/6.0f) * xi  * xm1 * xm2;
  float w1 =  0.5f        * xp1 * xm1 * xm2;
  float w2 = -0.5f        * xi  * xp1 * xm2;
  float w3 =  (1.0f/6.0f) * xi  * xp1 * xm1;
  return ((w0*y0 + w1*y1) + w2*y2) + w3*y3;
}
__global__ void k_tabFine(const float* __restrict__ Gtab, float* __restrict__ TabF){
  int m = blockIdx.x*blockDim.x + threadIdx.x;
  if (m >= T_STEPS*FKN) return;
  int t = m / FKN;
  int c = m - t*FKN;
  TabF[m] = cubicEval(Gtab + t*UKNOTS, c);
}

// linear interp on scalar fine table: two b32 LDS reads (bank ~2-way, free)
__device__ __forceinline__ float interpS(const float* __restrict__ tab, float s){
  float x = sqrtf(s) * 2048.0f;
  float cf = floorf(x);
  cf = fminf(cf, 2047.0f);
  int c = (int)cf;
  float xi = x - cf;
  float y0 = tab[c], y1 = tab[c+1];
  return fmaf(xi, y1 - y0, y0);
}

// ---------------- kernel 5: sequential particle filter (single block, 1024 thr) ----------------
// 2 barriers/step. idxA uses step-tags (t*8192+i) so no clearing and no WAR barrier.
// LDS table double-buffered; socProp double-buffered in global scratch.
__global__ __launch_bounds__(1024) void k_filter(
    const float* __restrict__ soc_init, const float* __restrict__ current,
    const float* __restrict__ vmeas,   const float* __restrict__ Ecrit,
    const float* __restrict__ TabF,    const float* __restrict__ noiseTab,
    const float* __restrict__ u0Tab,   float* __restrict__ socBuf,   // 2*N_PART floats
    float* __restrict__ vHist, float* __restrict__ sHist,
    long strideT, long strideP, float* __restrict__ lossOut)
{
  __shared__ __align__(16) int   idxA[N_PART];     // 32 KiB
  __shared__ __align__(16) float tabF[2][2052];    // 16.4 KiB (dbuf)
  __shared__ float ddW[16];
  __shared__ float sWv[16];

  const int tid = threadIdx.x;
  const int lane = tid & 63;
  const int wv = tid >> 6;
  const float ec = Ecrit[0];

  // prologue: idxA init (tags are always >= 0), table row 0, noise row 0
  { int4 mm1 = {-1,-1,-1,-1}; ((int4*)idxA)[tid*2] = mm1; ((int4*)idxA)[tid*2+1] = mm1; }
  tabF[0][tid]      = TabF[tid];
  tabF[0][1024+tid] = TabF[1024+tid];
  if (tid == 0) tabF[0][2048] = TabF[2048];
  const float4* nzp = (const float4*)noiseTab + tid*2;
  float4 nzA = nzp[0], nzB = nzp[1];
  float soc[8], V[8];
  __syncthreads();
  #pragma unroll
  for (int k=0;k<8;k++){
    float s = soc_init[tid*8+k];
    soc[k] = s;
    V[k] = interpS(tabF[0], s);
  }
  float loss = 0.0f;
  float Iprev = current[0];

  for (int t=0; t<T_STEPS; t++){
    const int cur = t & 1, nxt = cur ^ 1;
    const int tagBase = t << 13;
    float* socCur = socBuf + (size_t)cur * N_PART;

    // ---- prefetch next-step table + noise (global) ----
    int tn = (t+1 < T_STEPS) ? t+1 : t;
    const float* tRow = TabF + (size_t)tn * FKN;
    float pf0 = tRow[tid];
    float pf1 = tRow[1024+tid];
    float pf2 = 0.0f;
    if (tid == 0) pf2 = tRow[2048];
    const float4* nzn = (const float4*)(noiseTab + (size_t)tn*N_PART) + tid*2;
    float4 nzA2 = nzn[0], nzB2 = nzn[1];

    float It = current[t];
    float vm = vmeas[t];
    float u0 = u0Tab[t];
    float coef = -(Iprev / 26267.160775850585f) * ec;   // fused propagate coefficient
    float nz[8] = {nzA.x,nzA.y,nzA.z,nzA.w,nzB.x,nzB.y,nzB.z,nzB.w};
    const float* tf = tabF[cur];

    // ---- phase 1: propagate + measure (dd = (V-vm)^2; lw = LOGNU - 5000*dd) ----
    float sp[8], dd[8];
    float dmin = INFINITY;
    #pragma unroll
    for (int k=0;k<8;k++){
      float s = fmaf(V[k], coef, soc[k]);
      s = s + nz[k];
      s = fminf(1.0f, fmaxf(s, 1e-10f));   // med3 clamp (ref's [0,1e-10) corner is measure-zero)
      sp[k] = s;
      float Vn = interpS(tf, s);
      V[k] = Vn;
      float d = Vn - vm;
      float q = d*d;
      dd[k] = q;
      dmin = fminf(dmin, q);
    }
    { // propagated state -> global dbuf (exact f32)
      float4 a = {sp[0],sp[1],sp[2],sp[3]}, b = {sp[4],sp[5],sp[6],sp[7]};
      float4* dst = (float4*)(socCur + tid*8);
      dst[0] = a; dst[1] = b;
    }
    if (strideP == 1){
      float4 a = {V[0],V[1],V[2],V[3]}, b = {V[4],V[5],V[6],V[7]};
      float4* dst = (float4*)(vHist + (size_t)t*strideT + tid*8);
      dst[0] = a; dst[1] = b;
    } else {
      #pragma unroll
      for (int k=0;k<8;k++) vHist[(size_t)t*strideT + (size_t)(tid*8+k)*strideP] = V[k];
    }

    // commit prefetched table into the other LDS buffer (read at t+1)
    tabF[nxt][tid]      = pf0;
    tabF[nxt][1024+tid] = pf1;
    if (tid == 0) tabF[nxt][2048] = pf2;

    // ---- wave reduce: min dd, then exp prefix (wave frame) ----
    #pragma unroll
    for (int off=1; off<64; off<<=1) dmin = fminf(dmin, __shfl_xor(dmin, off));
    float ebase = DD2E * dmin;
    float run = 0.0f, cp[8];
    #pragma unroll
    for (int k=0;k<8;k++){
      float e = exp2f(fmaf(dd[k], -DD2E, ebase));
      run += e;
      cp[k] = run;
    }
    float sc = run;
    #pragma unroll
    for (int off=1; off<64; off<<=1){
      float o = __shfl_up(sc, (unsigned)off);
      if (lane >= off) sc += o;
    }
    float excl = sc - run;
    if (lane == 63){ ddW[wv] = dmin; sWv[wv] = sc; }
    __syncthreads();                        // B1

    // ---- combine wave stats (lanes 0..15 of every wave, no barrier) ----
    float baseV = 0.0f, scaleV = 0.0f;
    if (lane < 16){
      float dv = ddW[lane];
      float dG = dv;
      #pragma unroll
      for (int off=1; off<16; off<<=1) dG = fminf(dG, __shfl_xor(dG, off));
      float ew = exp2f(-DD2E * (dv - dG));
      float term = sWv[lane] * ew;
      float pf = term;
      #pragma unroll
      for (int off=1; off<16; off<<=1){
        float o = __shfl_up(pf, (unsigned)off);
        if (lane >= off) pf += o;
      }
      float Sv = __shfl(pf, 15);
      float invS = 1.0f / Sv;
      baseV  = (pf - term) * invS;
      scaleV = ew * invS;
      if (tid == 0)
        loss = ((loss + (LOGNU - DD2LW*dG)) + logf(Sv)) - LOG8192;
    }
    float b0  = __shfl(baseV, wv);
    float scl = __shfl(scaleV, wv);

    // ---- slot inversion + tagged scatter ----
    float scl8 = scl * 8192.0f;
    float bth  = fmaf(excl, scl8, fmaf(b0, 8192.0f, -u0));
    int aPrev = __float2int_rd(bth);
    if (aPrev < -1) aPrev = -1;
    #pragma unroll
    for (int k=0;k<8;k++){
      int i = tid*8 + k;
      int a = __float2int_rd(fmaf(cp[k], scl8, bth));
      if (a > N_PART-1) a = N_PART-1;
      if (i == N_PART-1) a = N_PART-1;      // safety: last particle owns last slot
      if (a < aPrev) a = aPrev;
      int st = aPrev + 1;
      int tag = tagBase + i;
      if (st < N_PART) atomicMax(&idxA[st], tag);
      for (int r = (st>>9)+1; (r<<9) <= a; ++r)
        atomicMax(&idxA[r<<9], tag);        // 512-region anchors
      aPrev = a;
    }
    __syncthreads();                        // B2

    // ---- wave max-scan over slots + gather (tags beat stale entries) ----
    int4 q0 = ((const int4*)idxA)[tid*2];
    int4 q1 = ((const int4*)idxA)[tid*2+1];
    int sl[8] = {q0.x,q0.y,q0.z,q0.w,q1.x,q1.y,q1.z,q1.w};
    int pm = sl[0];
    #pragma unroll
    for (int k=1;k<8;k++) pm = max(pm, sl[k]);
    int scn = pm;
    #pragma unroll
    for (int off=1; off<64; off<<=1){
      int o = __shfl_up(scn, (unsigned)off);
      if (lane >= off) scn = max(scn, o);
    }
    int ex = __shfl_up(scn, 1);
    if (lane == 0) ex = -1;                 // region start is a guaranteed fresh anchor
    const float* gBase = socCur - (size_t)tagBase;   // fold tag offset into base
    int run2 = ex;
    float sn[8];
    #pragma unroll
    for (int k=0;k<8;k++){
      run2 = max(run2, sl[k]);
      sn[k] = gBase[run2];
    }
    if (strideP == 1){
      float4 a = {sn[0],sn[1],sn[2],sn[3]}, b = {sn[4],sn[5],sn[6],sn[7]};
      float4* dst = (float4*)(sHist + (size_t)t*strideT + tid*8);
      dst[0] = a; dst[1] = b;
    } else {
      #pragma unroll
      for (int k=0;k<8;k++) sHist[(size_t)t*strideT + (size_t)(tid*8+k)*strideP] = sn[k];
    }
    #pragma unroll
    for (int k=0;k<8;k++) soc[k] = sn[k];
    Iprev = It;
    nzA = nzA2; nzB = nzB2;
    // no B3: socBuf is double-buffered; idxA tags make stale entries harmless;
    // tabF[nxt] writes are ordered by B1/B2 before any t+1 reader.
  }
  if (tid == 0) lossOut[0] = loss;
}

// ---------------- kernel 6: (T,N) -> (N,T) transpose ----------------
__global__ void k_transpose(const float* __restrict__ vS, const float* __restrict__ sS,
                            float* __restrict__ outV, float* __restrict__ outS){
  __shared__ float tile[32][33];
  const float* src = blockIdx.z ? sS : vS;
  float* dst = blockIdx.z ? outS : outV;
  int t0 = blockIdx.x*32, n0 = blockIdx.y*32;
  int tx = threadIdx.x, ty = threadIdx.y;
  #pragma unroll
  for (int r=0;r<4;r++)
    tile[ty+8*r][tx] = src[(size_t)(t0+ty+8*r)*N_PART + n0 + tx];
  __syncthreads();
  #pragma unroll
  for (int r=0;r<4;r++)
    dst[(size_t)(n0+ty+8*r)*T_STEPS + t0 + tx] = tile[tx][ty+8*r];
}

extern "C" void kernel_launch(void* const* d_in, const int* in_sizes, int n_in,
                              void* d_out, int out_size, void* d_ws, size_t ws_size,
                              hipStream_t stream){
  const float* soc_init = (const float*)d_in[0];
  const float* current  = (const float*)d_in[1];
  const float* vmeas    = (const float*)d_in[2];
  const float* W1 = (const float*)d_in[3];
  const float* b1 = (const float*)d_in[4];
  const float* W2 = (const float*)d_in[5];
  const float* b2 = (const float*)d_in[6];
  const float* W3 = (const float*)d_in[7];
  const float* b3 = (const float*)d_in[8];
  const float* Ec = (const float*)d_in[9];

  float* outLoss = (float*)d_out;
  float* outV = outLoss + 1;
  float* outS = outV + (size_t)N_PART*T_STEPS;

  char* p = (char*)d_ws;
  auto carve = [&](size_t bytes)->char*{ char* r = p; p += (bytes + 255) & ~(size_t)255; return r; };
  uint32_t* knKeys  = (uint32_t*)carve((size_t)2*T_STEPS*4);
  float* u0Tab      = (float*)carve((size_t)T_STEPS*4);
  float* socBuf     = (float*)carve((size_t)2*N_PART*4);
  float* Zpart      = (float*)carve((size_t)4*M2TOT*4);
  float* Z2D        = (float*)carve((size_t)M2TOT*4);
  float* Gtab       = (float*)carve((size_t)T_STEPS*UKNOTS*4);
  float* TabF       = (float*)carve((size_t)T_STEPS*FKN*4);
  float* noiseTab   = (float*)carve((size_t)N_PART*T_STEPS*4);
  float* vS         = (float*)carve((size_t)N_PART*T_STEPS*4);
  float* sS         = (float*)carve((size_t)N_PART*T_STEPS*4);
  bool useScratch   = ((size_t)(p - (char*)d_ws) <= ws_size);

  k_keys<<<dim3((T_STEPS+255)/256), dim3(256), 0, stream>>>(knKeys, u0Tab);
  k_noise<<<dim3(T_STEPS), dim3(256), 0, stream>>>(knKeys, noiseTab);
  k_gemm<<<dim3((M2TOT+63)/64, 4), dim3(256), 0, stream>>>(W1, b1, W2, b2, W3, Zpart);
  k_tabZ<<<dim3((M2TOT+255)/256), dim3(256), 0, stream>>>(Zpart, b3, Z2D);
  k_tabG<<<dim3((T_STEPS*UKNOTS+255)/256), dim3(256), 0, stream>>>(Z2D, current, Gtab);
  k_tabFine<<<dim3((T_STEPS*FKN+255)/256), dim3(256), 0, stream>>>(Gtab, TabF);

  if (useScratch){
    k_filter<<<dim3(1), dim3(1024), 0, stream>>>(soc_init, current, vmeas, Ec, TabF, noiseTab,
                                                 u0Tab, socBuf, vS, sS, (long)N_PART, 1L, outLoss);
    k_transpose<<<dim3(T_STEPS/32, N_PART/32, 2), dim3(32,8), 0, stream>>>(vS, sS, outV, outS);
  } else {
    k_filter<<<dim3(1), dim3(1024), 0, stream>>>(soc_init, current, vmeas, Ec, TabF, noiseTab,
                                                 u0Tab, socBuf, outV, outS, 1L, (long)T_STEPS, outLoss);
  }
}

// Round 9
// 6684.094 us; speedup vs baseline: 2.7150x; 1.3795x over previous
//
#include <hip/hip_runtime.h>
#include <stdint.h>
#include <math.h>

#define N_PART 8192
#define T_STEPS 1024
#define UKNOTS 130            // coarse u-knots k=0..129, u=k/128 (cubic source grid)
#define SIKNOTS 68            // sI-knots j=0..67, sI = SI_LO + j*SI_H
#define M2TOT (UKNOTS*SIKNOTS)
#define FKN 2049              // fine linear grid in u: entries c=0..2048, u=c/2048
#define SI_LO 0.49375f
#define SI_H  0.00625f
#define LOGNU 3.6862316527834183f
#define LOG8192 9.010913347279288f
#define DD2LW 5000.0f                 // lw = LOGNU - 5000*dd, dd=(V-vm)^2
#define DD2E  7213.4752044448170f     // 5000*log2(e)

// ---------------- Threefry-2x32 (exact JAX semantics) ----------------
__device__ __forceinline__ uint32_t rotl32(uint32_t x, int d){ return (x<<d)|(x>>(32-d)); }

__device__ __forceinline__ void tf2x32(uint32_t k0, uint32_t k1, uint32_t c0, uint32_t c1,
                                       uint32_t& o0, uint32_t& o1){
  uint32_t ks2 = k0 ^ k1 ^ 0x1BD11BDAu;
  uint32_t x0 = c0 + k0, x1 = c1 + k1;
  #define TFR(r) { x0 += x1; x1 = rotl32(x1, r); x1 ^= x0; }
  TFR(13) TFR(15) TFR(26) TFR(6)
  x0 += k1;  x1 += ks2 + 1u;
  TFR(17) TFR(29) TFR(16) TFR(24)
  x0 += ks2; x1 += k0 + 2u;
  TFR(13) TFR(15) TFR(26) TFR(6)
  x0 += k0;  x1 += k1 + 3u;
  TFR(17) TFR(29) TFR(16) TFR(24)
  x0 += k1;  x1 += ks2 + 4u;
  TFR(13) TFR(15) TFR(26) TFR(6)
  x0 += ks2; x1 += k0 + 5u;
  #undef TFR
  o0 = x0; o1 = x1;
}

__device__ __forceinline__ float erfinv_xla(float x){
  float w = -log1pf(-x*x);
  float p;
  if (w < 5.0f){
    w -= 2.5f;
    p = 2.81022636e-08f;
    p = fmaf(p, w, 3.43273939e-07f);
    p = fmaf(p, w, -3.5233877e-06f);
    p = fmaf(p, w, -4.39150654e-06f);
    p = fmaf(p, w, 0.00021858087f);
    p = fmaf(p, w, -0.00125372503f);
    p = fmaf(p, w, -0.00417768164f);
    p = fmaf(p, w, 0.246640727f);
    p = fmaf(p, w, 1.50140941f);
  } else {
    w = sqrtf(w) - 3.0f;
    p = -0.000200214257f;
    p = fmaf(p, w, 0.000100950558f);
    p = fmaf(p, w, 0.00134934322f);
    p = fmaf(p, w, -0.00367342844f);
    p = fmaf(p, w, 0.00573950773f);
    p = fmaf(p, w, -0.0076224613f);
    p = fmaf(p, w, 0.00943887047f);
    p = fmaf(p, w, 1.00167406f);
    p = fmaf(p, w, 2.83297682f);
  }
  return p * x;
}

// ---------------- kernel 1: per-step keys + u0 ----------------
__global__ void k_keys(uint32_t* __restrict__ knKeys, float* __restrict__ u0Tab){
  int t = blockIdx.x*blockDim.x + threadIdx.x;
  if (t >= T_STEPS) return;
  uint32_t kA0,kA1,kB0,kB1;
  tf2x32(0u,42u, 0u,0u, kA0,kA1);
  tf2x32(0u,42u, 0u,1u, kB0,kB1);
  auto splitElem = [&](uint32_t kk0, uint32_t kk1, int idx)->uint32_t{
    uint32_t o0,o1;
    if (idx < T_STEPS){ tf2x32(kk0,kk1,(uint32_t)idx,(uint32_t)(T_STEPS+idx),o0,o1); return o0; }
    int i = idx - T_STEPS;
    tf2x32(kk0,kk1,(uint32_t)i,(uint32_t)(T_STEPS+i),o0,o1); return o1;
  };
  uint32_t n0 = splitElem(kA0,kA1, 2*t);
  uint32_t n1 = splitElem(kA0,kA1, 2*t+1);
  uint32_t r0 = splitElem(kB0,kB1, 2*t);
  uint32_t r1 = splitElem(kB0,kB1, 2*t+1);
  knKeys[2*t] = n0; knKeys[2*t+1] = n1;
  uint32_t o0,o1; tf2x32(r0,r1,0u,0u,o0,o1);
  u0Tab[t] = __uint_as_float((o0>>9) | 0x3f800000u) - 1.0f;
}

// ---------------- kernel 2: noise table ----------------
__global__ void k_noise(const uint32_t* __restrict__ knKeys, float* __restrict__ noiseTab){
  int t = blockIdx.x;
  uint32_t k0 = knKeys[2*t], k1 = knKeys[2*t+1];
  const int half = N_PART/2;
  const float lo = -0.99999994f;
  for (int i = threadIdx.x; i < half; i += blockDim.x){
    uint32_t o0,o1; tf2x32(k0,k1,(uint32_t)i,(uint32_t)(half+i),o0,o1);
    float ua = __uint_as_float((o0>>9)|0x3f800000u) - 1.0f;
    float ub = __uint_as_float((o1>>9)|0x3f800000u) - 1.0f;
    float va = fmaxf(lo, ua*2.0f + lo);
    float vb = fmaxf(lo, ub*2.0f + lo);
    float na = 1.4142135623730951f * erfinv_xla(va);
    float nb = 1.4142135623730951f * erfinv_xla(vb);
    noiseTab[(size_t)t*N_PART + i]        = 0.005f * na;
    noiseTab[(size_t)t*N_PART + half + i] = 0.005f * nb;
  }
}

// ---------------- kernel 3: (u, sI)-grid MLP GEMM ----------------
__global__ __launch_bounds__(256) void k_gemm(
    const float* __restrict__ W1, const float* __restrict__ b1,
    const float* __restrict__ W2, const float* __restrict__ b2,
    const float* __restrict__ W3, float* __restrict__ Zpart)
{
  __shared__ float sA[32][64];
  __shared__ float sB[32][129];
  __shared__ float sSoc[64], sSI[64];
  __shared__ float sRed[64][17];

  const int tid = threadIdx.x;
  const int m0 = blockIdx.x * 64;
  const int n0 = blockIdx.y * 128;

  if (tid < 64){
    int r = m0 + tid; if (r >= M2TOT) r = M2TOT-1;
    int k = r / SIKNOTS;
    int j = r - k*SIKNOTS;
    float u = (float)k * (1.0f/128.0f);
    sSoc[tid] = u*u;
    sSI[tid]  = SI_LO + SI_H * (float)j;
  }
  __syncthreads();

  const int tx = tid & 15;
  const int ty = tid >> 4;
  float acc[4][8];
  #pragma unroll
  for (int i=0;i<4;i++)
    #pragma unroll
    for (int q=0;q<8;q++) acc[i][q] = 0.0f;

  for (int kc = 0; kc < 1024; kc += 32){
    {
      int base = tid*8;
      int jj = base >> 6;
      int mm = base & 63;
      int j = kc + jj;
      float w0 = W1[2*j], w1v = W1[2*j+1], bb = b1[j];
      #pragma unroll
      for (int e=0;e<8;e++){
        int m = mm + e;
        float pre = sSoc[m]*w0 + sSI[m]*w1v + bb;
        sA[jj][m] = 1.0f/(1.0f + expf(-pre));
      }
    }
    {
      int nl = tid & 127;
      int h  = tid >> 7;
      const float* src = W2 + (size_t)(n0 + nl)*1024 + kc + h*16;
      float4 v0 = *(const float4*)(src+0);
      float4 v1 = *(const float4*)(src+4);
      float4 v2 = *(const float4*)(src+8);
      float4 v3 = *(const float4*)(src+12);
      int kb = h*16;
      sB[kb+ 0][nl]=v0.x; sB[kb+ 1][nl]=v0.y; sB[kb+ 2][nl]=v0.z; sB[kb+ 3][nl]=v0.w;
      sB[kb+ 4][nl]=v1.x; sB[kb+ 5][nl]=v1.y; sB[kb+ 6][nl]=v1.z; sB[kb+ 7][nl]=v1.w;
      sB[kb+ 8][nl]=v2.x; sB[kb+ 9][nl]=v2.y; sB[kb+10][nl]=v2.z; sB[kb+11][nl]=v2.w;
      sB[kb+12][nl]=v3.x; sB[kb+13][nl]=v3.y; sB[kb+14][nl]=v3.z; sB[kb+15][nl]=v3.w;
    }
    __syncthreads();
    #pragma unroll
    for (int kk=0;kk<32;kk++){
      float a_[4], b_[8];
      #pragma unroll
      for (int i=0;i<4;i++) a_[i] = sA[kk][ty*4+i];
      #pragma unroll
      for (int q=0;q<8;q++) b_[q] = sB[kk][tx*8+q];
      #pragma unroll
      for (int i=0;i<4;i++)
        #pragma unroll
        for (int q=0;q<8;q++) acc[i][q] = fmaf(a_[i], b_[q], acc[i][q]);
    }
    __syncthreads();
  }
  float part[4] = {0.f,0.f,0.f,0.f};
  #pragma unroll
  for (int q=0;q<8;q++){
    int n = n0 + tx*8 + q;
    float bb = b2[n], w3 = W3[n];
    #pragma unroll
    for (int i=0;i<4;i++){
      float h = 1.0f/(1.0f + expf(-(acc[i][q] + bb)));
      part[i] = fmaf(w3, h, part[i]);
    }
  }
  #pragma unroll
  for (int i=0;i<4;i++) sRed[ty*4+i][tx] = part[i];
  __syncthreads();
  if (tid < 64){
    int r = m0 + tid;
    if (r < M2TOT){
      float s = 0.0f;
      #pragma unroll
      for (int x=0;x<16;x++) s += sRed[tid][x];
      Zpart[(size_t)blockIdx.y*M2TOT + r] = s;
    }
  }
}

// ---------------- kernel 4a: combine Z parts ----------------
__global__ void k_tabZ(const float* __restrict__ Zpart, const float* __restrict__ b3,
                       float* __restrict__ Z2D){
  int r = blockIdx.x*blockDim.x + threadIdx.x;
  if (r >= M2TOT) return;
  Z2D[r] = ((Zpart[r] + Zpart[M2TOT+r]) + Zpart[2*M2TOT+r]) + Zpart[3*M2TOT+r] + b3[0];
}

// ---------------- kernel 4b: per-(t,k) sI-interp + voc -> coarse G table ----------------
__global__ void k_tabG(const float* __restrict__ Z2D, const float* __restrict__ current,
                       float* __restrict__ Gtab){
  int m = blockIdx.x*blockDim.x + threadIdx.x;
  if (m >= T_STEPS*UKNOTS) return;
  int t = m / UKNOTS;
  int k = m - t*UKNOTS;
  float It = current[t];
  float sI = (It + 2.0f) * 0.25f;
  float x = (sI - SI_LO) * (1.0f/SI_H);
  int c = (int)x; if (c < 1) c = 1; if (c > 65) c = 65;
  float xi = x - (float)c;
  const float* zp = Z2D + k*SIKNOTS + (c-1);
  float y0 = zp[0], y1 = zp[1], y2 = zp[2], y3 = zp[3];
  float xm1 = xi - 1.0f, xm2 = xi - 2.0f, xp1 = xi + 1.0f;
  float w0 = -(1.0f/6.0f) * xi  * xm1 * xm2;
  float w1 =  0.5f        * xp1 * xm1 * xm2;
  float w2 = -0.5f        * xi  * xp1 * xm2;
  float w3 =  (1.0f/6.0f) * xi  * xp1 * xm1;
  float z = ((w0*y0 + w1*y1) + w2*y2) + w3*y3;
  double u = (double)k / 128.0;
  double s = u*u;
  const double vL=-1.59614486, v0=4.13646328, gam=0.63726463, alp=1.40174122, bet=2.54478965;
  double voc = vL + (v0-vL)*exp(gam*(s-1.0)) + alp*vL*(s-1.0)
             + (1.0-alp)*vL*(exp(-bet) - exp(-bet*sqrt(s)));
  Gtab[m] = (float)voc - It*z;
}

// ---------------- kernel 4c: coarse cubic -> fine scalar table ----------------
__device__ __forceinline__ float cubicEval(const float* __restrict__ g, int cf){
  float x = (float)cf * (1.0f/16.0f);
  int cc = (int)x; if (cc > 127) cc = 127;
  float xi = x - (float)cc;
  float y0 = (cc == 0) ? g[1] : g[cc-1];   // even mirror in u
  float y1 = g[cc], y2 = g[cc+1], y3 = g[cc+2];
  float xm1 = xi - 1.0f, xm2 = xi - 2.0f, xp1 = xi + 1.0f;
  float w0 = -(1.0f/6.0f) * xi  * xm1 * xm2;
  float w1 =  0.5f        * xp1 * xm1 * xm2;
  float w2 = -0.5f        * xi  * xp1 * xm2;
  float w3 =  (1.0f/6.0f) * xi  * xp1 * xm1;
  return ((w0*y0 + w1*y1) + w2*y2) + w3*y3;
}
__global__ void k_tabFine(const float* __restrict__ Gtab, float* __restrict__ TabF){
  int m = blockIdx.x*blockDim.x + threadIdx.x;
  if (m >= T_STEPS*FKN) return;
  int t = m / FKN;
  int c = m - t*FKN;
  TabF[m] = cubicEval(Gtab + t*UKNOTS, c);
}

// linear interp on scalar fine table (LDS)
__device__ __forceinline__ float interpS(const float* __restrict__ tab, float s){
  float x = sqrtf(s) * 2048.0f;
  float cf = floorf(x);
  cf = fminf(cf, 2047.0f);
  int c = (int)cf;
  float xi = x - cf;
  float y0 = tab[c], y1 = tab[c+1];
  return fmaf(xi, y1 - y0, y0);
}

// ---------------- kernel 5: sequential particle filter (single block, 1024 thr) ----------------
// R4 structure + (a) socP in LDS (exact f32), (b) idxG tagged in GLOBAL (no LDS atomics,
// no clearing; 0xAA poison < 0 always loses), (c) bitwise-exact thread/wave seams,
// (d) atomics only for particles owning >=1 slot. 3 barriers/step.
__global__ __launch_bounds__(1024) void k_filter(
    const float* __restrict__ soc_init, const float* __restrict__ current,
    const float* __restrict__ vmeas,   const float* __restrict__ Ecrit,
    const float* __restrict__ TabF,    const float* __restrict__ noiseTab,
    const float* __restrict__ u0Tab,   int* __restrict__ idxG,
    float* __restrict__ vHist, float* __restrict__ sHist,
    long strideT, long strideP, float* __restrict__ lossOut)
{
  __shared__ __align__(16) float socP[N_PART];     // 32 KiB (exact f32 propagated state)
  __shared__ __align__(16) float tabF[2][2052];    // 16.4 KiB dbuf
  __shared__ float ddW[16];
  __shared__ float sWv[16];

  const int tid = threadIdx.x;
  const int lane = tid & 63;
  const int wv = tid >> 6;
  const float ec = Ecrit[0];

  // prologue
  tabF[0][tid]      = TabF[tid];
  tabF[0][1024+tid] = TabF[1024+tid];
  if (tid == 0) tabF[0][2048] = TabF[2048];
  const float4* nzp = (const float4*)noiseTab + tid*2;
  float4 nzA = nzp[0], nzB = nzp[1];
  float soc[8], V[8];
  __syncthreads();
  #pragma unroll
  for (int k=0;k<8;k++){
    float s = soc_init[tid*8+k];
    soc[k] = s;
    V[k] = interpS(tabF[0], s);
  }
  float loss = 0.0f;
  float Iprev = current[0];

  for (int t=0; t<T_STEPS; t++){
    const int cur = t & 1, nxt = cur ^ 1;
    const int tagBase = t << 13;

    // prefetch next-step table + noise into registers
    int tn = (t+1 < T_STEPS) ? t+1 : t;
    const float* tRow = TabF + (size_t)tn * FKN;
    float pf0 = tRow[tid];
    float pf1 = tRow[1024+tid];
    float pf2 = 0.0f;
    if (tid == 0) pf2 = tRow[2048];
    const float4* nzn = (const float4*)(noiseTab + (size_t)tn*N_PART) + tid*2;
    float4 nzA2 = nzn[0], nzB2 = nzn[1];

    float It = current[t];
    float vm = vmeas[t];
    float u0 = u0Tab[t];
    float coef = -(Iprev / 26267.160775850585f) * ec;
    float nz[8] = {nzA.x,nzA.y,nzA.z,nzA.w,nzB.x,nzB.y,nzB.z,nzB.w};
    const float* tf = tabF[cur];

    // ---- phase 1: propagate + measure (socP write in LDS, exact f32) ----
    float dd[8];
    float dmin = INFINITY;
    #pragma unroll
    for (int k=0;k<8;k++){
      float s = fmaf(V[k], coef, soc[k]);
      s = s + nz[k];
      s = fminf(1.0f, fmaxf(s, 1e-10f));
      socP[tid*8+k] = s;
      float Vn = interpS(tf, s);
      V[k] = Vn;
      float d = Vn - vm;
      float q = d*d;
      dd[k] = q;
      dmin = fminf(dmin, q);
    }
    if (strideP == 1){
      float4 a = {V[0],V[1],V[2],V[3]}, b = {V[4],V[5],V[6],V[7]};
      float4* dst = (float4*)(vHist + (size_t)t*strideT + tid*8);
      dst[0] = a; dst[1] = b;
    } else {
      #pragma unroll
      for (int k=0;k<8;k++) vHist[(size_t)t*strideT + (size_t)(tid*8+k)*strideP] = V[k];
    }

    // wave min + exp prefix (wave frame)
    #pragma unroll
    for (int off=1; off<64; off<<=1) dmin = fminf(dmin, __shfl_xor(dmin, off));
    float ebase = DD2E * dmin;
    float run = 0.0f, cp[8];
    #pragma unroll
    for (int k=0;k<8;k++){
      float e = exp2f(fmaf(dd[k], -DD2E, ebase));
      run += e;
      cp[k] = run;
    }
    float sc = run;
    #pragma unroll
    for (int off=1; off<64; off<<=1){
      float o = __shfl_up(sc, (unsigned)off);
      if (lane >= off) sc += o;
    }
    float excl = __shfl_up(sc, 1);       // bitwise == prev lane's inclusive sc
    if (lane == 0) excl = 0.0f;
    if (lane == 63){ ddW[wv] = dmin; sWv[wv] = sc; }
    // commit prefetched table into the other buffer
    tabF[nxt][tid]      = pf0;
    tabF[nxt][1024+tid] = pf1;
    if (tid == 0) tabF[nxt][2048] = pf2;
    __syncthreads();                     // B1

    // ---- combine wave stats (lanes 0..15 of every wave, redundant; normalized frames) ----
    float baseN = 0.0f, inclN = 0.0f, scaleN = 0.0f;
    if (lane < 16){
      float dv = ddW[lane];
      float dG = dv;
      #pragma unroll
      for (int off=1; off<16; off<<=1) dG = fminf(dG, __shfl_xor(dG, off));
      float ew = exp2f(-DD2E * (dv - dG));
      float pf = sWv[lane] * ew;
      #pragma unroll
      for (int off=1; off<16; off<<=1){
        float o = __shfl_up(pf, (unsigned)off);
        if (lane >= off) pf += o;
      }
      float Sv = __shfl(pf, 15);
      float invS = 1.0f / Sv;
      float pfEx = __shfl_up(pf, 1);
      if (lane == 0) pfEx = 0.0f;
      baseN  = pfEx * invS;              // exclusive block prefix, normalized
      inclN  = pf * invS;                // inclusive; bitwise == next wave's baseN
      scaleN = ew * invS;
      if (tid == 0)
        loss = ((loss + (LOGNU - DD2LW*dG)) + logf(Sv)) - LOG8192;
    }
    float b0  = __shfl(baseN, wv);
    float bI  = __shfl(inclN, wv);
    float scl = __shfl(scaleN, wv);

    // ---- slot inversion + tagged GLOBAL scatter (bitwise-exact seams, owners only) ----
    float scl8 = scl * 8192.0f;
    float b8   = fmaf(b0, 8192.0f, -u0);       // wave base in slot units
    float bth  = fmaf(excl, scl8, b8);
    int aPrev = __float2int_rd(bth);
    if (aPrev < -1) aPrev = -1;
    #pragma unroll
    for (int k=0;k<8;k++){
      int i = tid*8 + k;
      int a;
      if (i == N_PART-1){
        a = N_PART-1;
      } else if (k == 7){
        if (lane == 63) a = __float2int_rd(fmaf(bI, 8192.0f, -u0));  // == next wave's aPrev
        else            a = __float2int_rd(fmaf(sc, scl8, b8));      // == next thread's aPrev
        if (a > N_PART-1) a = N_PART-1;
      } else {
        a = __float2int_rd(fmaf(cp[k], scl8, bth));
        if (a > N_PART-1) a = N_PART-1;
      }
      if (a < aPrev) a = aPrev;
      int st = aPrev + 1;
      if (a >= st){                              // owners only
        int tag = tagBase + i;
        atomicMax(&idxG[st], tag);
        for (int r = (st>>9)+1; (r<<9) <= a; ++r)
          atomicMax(&idxG[r<<9], tag);           // 512-region anchors
      }
      aPrev = a;
    }
    __syncthreads();                     // B2 (drains atomics; socP visible)

    // ---- slot phase: agent-scope idxG reads (L1-bypass), wave max-scan, LDS gather ----
    unsigned long long q01 = __hip_atomic_load((unsigned long long*)&idxG[tid*8+0], __ATOMIC_RELAXED, __HIP_MEMORY_SCOPE_AGENT);
    unsigned long long q23 = __hip_atomic_load((unsigned long long*)&idxG[tid*8+2], __ATOMIC_RELAXED, __HIP_MEMORY_SCOPE_AGENT);
    unsigned long long q45 = __hip_atomic_load((unsigned long long*)&idxG[tid*8+4], __ATOMIC_RELAXED, __HIP_MEMORY_SCOPE_AGENT);
    unsigned long long q67 = __hip_atomic_load((unsigned long long*)&idxG[tid*8+6], __ATOMIC_RELAXED, __HIP_MEMORY_SCOPE_AGENT);
    int sl[8] = { (int)(uint32_t)q01, (int)(uint32_t)(q01>>32),
                  (int)(uint32_t)q23, (int)(uint32_t)(q23>>32),
                  (int)(uint32_t)q45, (int)(uint32_t)(q45>>32),
                  (int)(uint32_t)q67, (int)(uint32_t)(q67>>32) };
    int pm = sl[0];
    #pragma unroll
    for (int k=1;k<8;k++) pm = max(pm, sl[k]);
    int scn = pm;
    #pragma unroll
    for (int off=1; off<64; off<<=1){
      int o = __shfl_up(scn, (unsigned)off);
      if (lane >= off) scn = max(scn, o);
    }
    int ex = __shfl_up(scn, 1);
    if (lane == 0) ex = -1;              // wave-chunk start covered by 512-anchor
    float sn[8];
    int run2 = ex;
    #pragma unroll
    for (int k=0;k<8;k++){
      run2 = max(run2, sl[k]);
      int idx = run2 - tagBase;
      if (idx < 0 || idx > N_PART-1) idx = tid*8+k;   // safety net (should not trigger)
      sn[k] = socP[idx];
    }
    if (strideP == 1){
      float4 a = {sn[0],sn[1],sn[2],sn[3]}, b = {sn[4],sn[5],sn[6],sn[7]};
      float4* dst = (float4*)(sHist + (size_t)t*strideT + tid*8);
      dst[0] = a; dst[1] = b;
    } else {
      #pragma unroll
      for (int k=0;k<8;k++) sHist[(size_t)t*strideT + (size_t)(tid*8+k)*strideP] = sn[k];
    }
    #pragma unroll
    for (int k=0;k<8;k++) soc[k] = sn[k];
    Iprev = It;
    nzA = nzA2; nzB = nzB2;
    __syncthreads();                     // B3 (WAR: socP gather vs next-step writes)
  }
  if (tid == 0) lossOut[0] = loss;
}

// ---------------- kernel 6: (T,N) -> (N,T) transpose ----------------
__global__ void k_transpose(const float* __restrict__ vS, const float* __restrict__ sS,
                            float* __restrict__ outV, float* __restrict__ outS){
  __shared__ float tile[32][33];
  const float* src = blockIdx.z ? sS : vS;
  float* dst = blockIdx.z ? outS : outV;
  int t0 = blockIdx.x*32, n0 = blockIdx.y*32;
  int tx = threadIdx.x, ty = threadIdx.y;
  #pragma unroll
  for (int r=0;r<4;r++)
    tile[ty+8*r][tx] = src[(size_t)(t0+ty+8*r)*N_PART + n0 + tx];
  __syncthreads();
  #pragma unroll
  for (int r=0;r<4;r++)
    dst[(size_t)(n0+ty+8*r)*T_STEPS + t0 + tx] = tile[tx][ty+8*r];
}

extern "C" void kernel_launch(void* const* d_in, const int* in_sizes, int n_in,
                              void* d_out, int out_size, void* d_ws, size_t ws_size,
                              hipStream_t stream){
  const float* soc_init = (const float*)d_in[0];
  const float* current  = (const float*)d_in[1];
  const float* vmeas    = (const float*)d_in[2];
  const float* W1 = (const float*)d_in[3];
  const float* b1 = (const float*)d_in[4];
  const float* W2 = (const float*)d_in[5];
  const float* b2 = (const float*)d_in[6];
  const float* W3 = (const float*)d_in[7];
  const float* b3 = (const float*)d_in[8];
  const float* Ec = (const float*)d_in[9];

  float* outLoss = (float*)d_out;
  float* outV = outLoss + 1;
  float* outS = outV + (size_t)N_PART*T_STEPS;

  char* p = (char*)d_ws;
  auto carve = [&](size_t bytes)->char*{ char* r = p; p += (bytes + 255) & ~(size_t)255; return r; };
  uint32_t* knKeys  = (uint32_t*)carve((size_t)2*T_STEPS*4);
  float* u0Tab      = (float*)carve((size_t)T_STEPS*4);
  int*   idxG       = (int*)carve((size_t)N_PART*4);     // 0xAA poison < 0 == stale, no init
  float* Zpart      = (float*)carve((size_t)4*M2TOT*4);
  float* Z2D        = (float*)carve((size_t)M2TOT*4);
  float* Gtab       = (float*)carve((size_t)T_STEPS*UKNOTS*4);
  float* TabF       = (float*)carve((size_t)T_STEPS*FKN*4);
  float* noiseTab   = (float*)carve((size_t)N_PART*T_STEPS*4);
  float* vS         = (float*)carve((size_t)N_PART*T_STEPS*4);
  float* sS         = (float*)carve((size_t)N_PART*T_STEPS*4);
  bool useScratch   = ((size_t)(p - (char*)d_ws) <= ws_size);

  k_keys<<<dim3((T_STEPS+255)/256), dim3(256), 0, stream>>>(knKeys, u0Tab);
  k_noise<<<dim3(T_STEPS), dim3(256), 0, stream>>>(knKeys, noiseTab);
  k_gemm<<<dim3((M2TOT+63)/64, 4), dim3(256), 0, stream>>>(W1, b1, W2, b2, W3, Zpart);
  k_tabZ<<<dim3((M2TOT+255)/256), dim3(256), 0, stream>>>(Zpart, b3, Z2D);
  k_tabG<<<dim3((T_STEPS*UKNOTS+255)/256), dim3(256), 0, stream>>>(Z2D, current, Gtab);
  k_tabFine<<<dim3((T_STEPS*FKN+255)/256), dim3(256), 0, stream>>>(Gtab, TabF);

  if (useScratch){
    k_filter<<<dim3(1), dim3(1024), 0, stream>>>(soc_init, current, vmeas, Ec, TabF, noiseTab,
                                                 u0Tab, idxG, vS, sS, (long)N_PART, 1L, outLoss);
    k_transpose<<<dim3(T_STEPS/32, N_PART/32, 2), dim3(32,8), 0, stream>>>(vS, sS, outV, outS);
  } else {
    k_filter<<<dim3(1), dim3(1024), 0, stream>>>(soc_init, current, vmeas, Ec, TabF, noiseTab,
                                                 u0Tab, idxG, outV, outS, 1L, (long)T_STEPS, outLoss);
  }
}